// Round 8
// baseline (631.359 us; speedup 1.0000x reference)
//
#include <hip/hip_runtime.h>
#include <hip/hip_fp16.h>
#include <math.h>

#define NN 50000
#define EE 800000
#define NHEAD 8
#define BN_EPS 1e-5f
#define NBIN 196            // ceil(NN/256) coarse buckets (dst>>8)
#define NBLK 64             // edge blocks per relation
#define EPB (EE / NBLK)     // 12500 edges per block (exact)
#define SCT (2 * NBIN * NBLK)  // 25088 scan elements = 98*256 exact
#define SCHUNK 98           // SCT / 256

typedef _Float16 half8_t __attribute__((ext_vector_type(8)));
typedef float float4_t __attribute__((ext_vector_type(4)));

// monotone float<->uint encoding for atomicMax on signed floats
__device__ __forceinline__ unsigned fenc(float f) {
  unsigned u = __float_as_uint(f);
  return (u & 0x80000000u) ? ~u : (u | 0x80000000u);
}
__device__ __forceinline__ float fdec(unsigned k) {
  return (k & 0x80000000u) ? __uint_as_float(k & 0x7fffffffu)
                           : __uint_as_float(~k);
}

// bn scale/shift from raw sums (stats[c]=sum, stats[128+c]=sumsq)
__device__ __forceinline__ void bn_coef(const float* __restrict__ stats,
                                        const float* __restrict__ gamma,
                                        const float* __restrict__ beta,
                                        int c, float& sc, float& sh) {
  float mean = stats[c] * (1.f / NN);
  float var = fmaxf(stats[128 + c] * (1.f / NN) - mean * mean, 0.f);
  sc = gamma[c] * rsqrtf(var + BN_EPS);
  sh = beta[c] - mean * sc;
}

// static lane swizzle (BitMode): new_lane = ((lane & and) | or) ^ xor, per 32-half
template <int PAT>
__device__ __forceinline__ float ds_swz(float x) {
  return __int_as_float(__builtin_amdgcn_ds_swizzle(__float_as_int(x), PAT));
}

// ---------------------------------------------------------------------------
// MFMA GEMM for embed/decision MLPs — R18 structure (128-row blocks, LDS
// pre-reduced STATS -> one global atomicAdd set per block). Unchanged in R19.
// ---------------------------------------------------------------------------
template <int KDIM, int NC, typename AT, bool ABN, bool RESIDBN, bool STATS,
          bool F16OUT, bool F32OUT>
__global__ __launch_bounds__(256)
void mfma_gemm_k(const AT* __restrict__ A, const _Float16* __restrict__ Bt,
                 const float* __restrict__ bn, const float* __restrict__ gamma,
                 const float* __restrict__ beta, float* __restrict__ statsOut,
                 const _Float16* __restrict__ residh, _Float16* __restrict__ Ch,
                 float* __restrict__ Cf, int M) {
  constexpr int NT = NC / 16;
  const int lane = threadIdx.x & 63, wave = threadIdx.x >> 6;
  const int q = lane >> 4, l16 = lane & 15;
  const int row0 = blockIdx.x * 128 + wave * 32;
  float4_t acc[2][NT];
#pragma unroll
  for (int i = 0; i < 2; ++i)
#pragma unroll
    for (int j = 0; j < NT; ++j) acc[i][j] = (float4_t){0.f, 0.f, 0.f, 0.f};

#pragma unroll
  for (int kk = 0; kk < KDIM / 32; ++kk) {
    float scv[8], shv[8];
    if constexpr (ABN) {
      int kb = kk * 32 + q * 8;
#pragma unroll
      for (int x = 0; x < 8; ++x) bn_coef(bn, gamma, beta, kb + x, scv[x], shv[x]);
    }
    half8_t a[2];
#pragma unroll
    for (int i = 0; i < 2; ++i) {
      int r = row0 + i * 16 + l16;
      r = (r < M) ? r : (M - 1);
      if constexpr (__is_same(AT, _Float16)) {
        half8_t hv = *(const half8_t*)(A + (size_t)r * KDIM + kk * 32 + q * 8);
        if constexpr (ABN) {
#pragma unroll
          for (int x = 0; x < 8; ++x)
            hv[x] = (_Float16)fmaxf((float)hv[x] * scv[x] + shv[x], 0.f);
        }
        a[i] = hv;
      } else {
        const float* ap = (const float*)A + (size_t)r * KDIM + kk * 32 + q * 8;
        float4 v0 = *(const float4*)ap, v1 = *(const float4*)(ap + 4);
        float t[8] = {v0.x, v0.y, v0.z, v0.w, v1.x, v1.y, v1.z, v1.w};
        if constexpr (ABN) {
#pragma unroll
          for (int x = 0; x < 8; ++x) t[x] = fmaxf(t[x] * scv[x] + shv[x], 0.f);
        }
        half8_t hv;
#pragma unroll
        for (int x = 0; x < 8; ++x) hv[x] = (_Float16)t[x];
        a[i] = hv;
      }
    }
#pragma unroll
    for (int j = 0; j < NT; ++j) {
      half8_t b = *(const half8_t*)(Bt + (size_t)(j * 16 + l16) * KDIM + kk * 32 + q * 8);
      acc[0][j] = __builtin_amdgcn_mfma_f32_16x16x32_f16(a[0], b, acc[0][j], 0, 0, 0);
      acc[1][j] = __builtin_amdgcn_mfma_f32_16x16x32_f16(a[1], b, acc[1][j], 0, 0, 0);
    }
  }

  float rsc[NT], rsh[NT];
  if constexpr (RESIDBN) {
#pragma unroll
    for (int j = 0; j < NT; ++j) bn_coef(bn, gamma, beta, j * 16 + l16, rsc[j], rsh[j]);
  }
#pragma unroll
  for (int i = 0; i < 2; ++i)
#pragma unroll
    for (int r = 0; r < 4; ++r) {
      int row = row0 + i * 16 + q * 4 + r;   // C/D: col=lane&15, row=q*4+reg
      if (row >= M) continue;
      float vv[NT];
#pragma unroll
      for (int j = 0; j < NT; ++j) {
        float v = acc[i][j][r];
        if constexpr (RESIDBN) {
          float rv = (float)residh[(size_t)row * NC + j * 16 + l16];
          v += fmaxf(rv * rsc[j] + rsh[j], 0.f);
        }
        vv[j] = v;
        if constexpr (F32OUT) Cf[(size_t)row * NC + j * 16 + l16] = v;
      }
      if constexpr (F16OUT) {
        // pair columns across lane pairs l16^1 (full-line packed __half2 stores)
        const bool ev = (l16 & 1) == 0;
#pragma unroll
        for (int jp = 0; jp < NT / 2; ++jp) {
          float a_ = vv[2 * jp], b_ = vv[2 * jp + 1];
          float an = ds_swz<(1 << 10) | 0x1F>(a_);
          float bn_ = ds_swz<(1 << 10) | 0x1F>(b_);
          float lo = ev ? a_ : bn_;
          float hi = ev ? an : b_;
          int jj = ev ? 2 * jp : 2 * jp + 1;
          __half2 hv = __floats2half2_rn(lo, hi);
          ((__half2*)Ch)[((size_t)row * NC + jj * 16 + (l16 & ~1)) >> 1] = hv;
        }
      }
    }

  if constexpr (STATS) {
    static_assert(!STATS || NT == 8, "stats layout assumes NC=128");
    __shared__ float reds[256];
    reds[threadIdx.x] = 0.f;
    __syncthreads();
    float sc_[NT], sq_[NT];
#pragma unroll
    for (int j = 0; j < NT; ++j) {
      float s = 0.f, qq = 0.f;
#pragma unroll
      for (int i = 0; i < 2; ++i)
#pragma unroll
        for (int r = 0; r < 4; ++r) {
          int row = row0 + i * 16 + q * 4 + r;
          float x = (row < M) ? acc[i][j][r] : 0.f;
          s += x; qq += x * x;
        }
      sc_[j] = s; sq_[j] = qq;
    }
#pragma unroll
    for (int j = 0; j < NT; ++j) {
      sc_[j] += __shfl_xor(sc_[j], 16, 64);
      sq_[j] += __shfl_xor(sq_[j], 16, 64);
      sc_[j] += __shfl_xor(sc_[j], 32, 64);
      sq_[j] += __shfl_xor(sq_[j], 32, 64);
    }
    if (lane < 16) {
#pragma unroll
      for (int j = 0; j < NT; ++j) {
        atomicAdd(&reds[j * 16 + l16], sc_[j]);        // LDS pre-reduction
        atomicAdd(&reds[128 + j * 16 + l16], sq_[j]);
      }
    }
    __syncthreads();
    atomicAdd(&statsOut[threadIdx.x], reds[threadIdx.x]);  // 1 set / block
  }
}

// ---------------------------------------------------------------------------
// Merged per-layer GAT GEMM, NC=288 — R18 structure (128-row blocks, LDS
// pre-reduced elmax -> one global atomicMax set per block). Unchanged in R19.
// ---------------------------------------------------------------------------
__global__ __launch_bounds__(256)
void feat_gemm_k(const _Float16* __restrict__ A, const _Float16* __restrict__ Bt,
                 _Float16* __restrict__ feat0, _Float16* __restrict__ feat1,
                 _Float16* __restrict__ el0h, float* __restrict__ er0,
                 _Float16* __restrict__ el1h, float* __restrict__ er1,
                 unsigned* __restrict__ elmax, int M) {
  constexpr int NT = 18;
  const int lane = threadIdx.x & 63, wave = threadIdx.x >> 6;
  const int q = lane >> 4, l16 = lane & 15;
  const int row0 = blockIdx.x * 128 + wave * 32;
  __shared__ unsigned redm[16];
  if (threadIdx.x < 16) redm[threadIdx.x] = 0u;
  float4_t acc[2][NT];
#pragma unroll
  for (int i = 0; i < 2; ++i)
#pragma unroll
    for (int j = 0; j < NT; ++j) acc[i][j] = (float4_t){0.f, 0.f, 0.f, 0.f};

#pragma unroll
  for (int kk = 0; kk < 4; ++kk) {
    half8_t a[2];
#pragma unroll
    for (int i = 0; i < 2; ++i) {
      int r = row0 + i * 16 + l16;
      r = (r < M) ? r : (M - 1);
      a[i] = *(const half8_t*)(A + (size_t)r * 128 + kk * 32 + q * 8);
    }
#pragma unroll
    for (int j = 0; j < NT; ++j) {
      half8_t b = *(const half8_t*)(Bt + (size_t)(j * 16 + l16) * 128 + kk * 32 + q * 8);
      acc[0][j] = __builtin_amdgcn_mfma_f32_16x16x32_f16(a[0], b, acc[0][j], 0, 0, 0);
      acc[1][j] = __builtin_amdgcn_mfma_f32_16x16x32_f16(a[1], b, acc[1][j], 0, 0, 0);
    }
  }

#pragma unroll
  for (int i = 0; i < 2; ++i)
#pragma unroll
    for (int r = 0; r < 4; ++r) {
      int row = row0 + i * 16 + q * 4 + r;
      if (row >= M) continue;
      const bool ev = (l16 & 1) == 0;
#pragma unroll
      for (int jp = 0; jp < 8; ++jp) {     // pairs (2jp, 2jp+1); no feat0/1 straddle
        float a_ = acc[i][2 * jp][r], b_ = acc[i][2 * jp + 1][r];
        float an = ds_swz<(1 << 10) | 0x1F>(a_);
        float bn_ = ds_swz<(1 << 10) | 0x1F>(b_);
        float lo = ev ? a_ : bn_;
        float hi = ev ? an : b_;
        int jj = ev ? 2 * jp : 2 * jp + 1;
        __half2 hv = __floats2half2_rn(lo, hi);
        _Float16* fb = (jj < 8) ? feat0 : feat1;
        int colbase = (jj < 8) ? jj * 16 : (jj - 8) * 16;
        ((__half2*)fb)[((size_t)row * 128 + colbase + (l16 & ~1)) >> 1] = hv;
      }
      {
        float v = acc[i][16][r];
        if (l16 < 8) el0h[(size_t)row * 8 + l16] = (_Float16)v;
        else         er0[(size_t)row * 8 + (l16 - 8)] = v;
        v = acc[i][17][r];
        if (l16 < 8) el1h[(size_t)row * 8 + l16] = (_Float16)v;
        else         er1[(size_t)row * 8 + (l16 - 8)] = v;
      }
    }

  float m0 = -1e30f, m1 = -1e30f;
#pragma unroll
  for (int i = 0; i < 2; ++i)
#pragma unroll
    for (int r = 0; r < 4; ++r) {
      m0 = fmaxf(m0, acc[i][16][r]);
      m1 = fmaxf(m1, acc[i][17][r]);
    }
  m0 = fmaxf(m0, __shfl_xor(m0, 16, 64)); m0 = fmaxf(m0, __shfl_xor(m0, 32, 64));
  m1 = fmaxf(m1, __shfl_xor(m1, 16, 64)); m1 = fmaxf(m1, __shfl_xor(m1, 32, 64));
  __syncthreads();                       // redm init visible to all waves
  if (q == 0 && l16 < 8) {
    atomicMax(&redm[l16], fenc(m0));     // LDS pre-reduction across waves
    atomicMax(&redm[8 + l16], fenc(m1));
  }
  __syncthreads();
  if (threadIdx.x < 16) atomicMax(&elmax[threadIdx.x], redm[threadIdx.x]);
}

// ---------------------------------------------------------------------------
// Build (R17 form, kept): tiled transposes + bhist merged. Grid = 305 blocks.
// ---------------------------------------------------------------------------
__global__ __launch_bounds__(256)
void build_k(const float* __restrict__ ew1, const float* __restrict__ ew2,
             const float* __restrict__ dw1, const float* __restrict__ dw2,
             const float* __restrict__ gfc, const float* __restrict__ gal,
             const float* __restrict__ gar, _Float16* __restrict__ ew1t,
             _Float16* __restrict__ ew2t, _Float16* __restrict__ dw1t,
             _Float16* __restrict__ dw2t, _Float16* __restrict__ bt,
             float* __restrict__ statsz, unsigned* __restrict__ elmax,
             const int* __restrict__ dstIdx, int* __restrict__ bcnt) {
  const int bid = blockIdx.x;

  if (bid < 172) {  // tiled transpose jobs
    const float* src; _Float16* dst; int K, N, kt, ct;
    if (bid < 8)       { src = ew1; dst = ew1t; K = 64;  N = 128; int t = bid;      kt = t >> 2; ct = t & 3; }
    else if (bid < 24) { src = ew2; dst = ew2t; K = 128; N = 128; int t = bid - 8;  kt = t >> 2; ct = t & 3; }
    else if (bid < 40) { src = dw1; dst = dw1t; K = 128; N = 128; int t = bid - 24; kt = t >> 2; ct = t & 3; }
    else if (bid < 44) { src = dw2; dst = dw2t; K = 128; N = 32;  int t = bid - 40; kt = t;      ct = 0;     }
    else {
      int idx = bid - 44;          // 8 mats x 16 tiles
      int mat = idx >> 4, t = idx & 15;
      int b = mat >> 1, r = mat & 1;
      src = gfc + (size_t)(2 * b + r) * 16384;
      dst = bt + (size_t)b * 288 * 128 + (size_t)r * 128 * 128;
      K = 128; N = 128; kt = t >> 2; ct = t & 3;
    }
    __shared__ float tile[32][33];
    int k0 = kt * 32, c0 = ct * 32;
    int tk = threadIdx.x >> 5, tc = threadIdx.x & 31;  // 8 k-rows x 32 c-cols
#pragma unroll
    for (int it = 0; it < 4; ++it) {
      int k = k0 + tk + it * 8;
      tile[tc][tk + it * 8] = src[(size_t)k * N + c0 + tc];  // coalesced in c
    }
    __syncthreads();
    int ci = threadIdx.x >> 5, ck = threadIdx.x & 31;  // 8 c-rows x 32 k-cols
#pragma unroll
    for (int it = 0; it < 4; ++it) {
      int c = c0 + ci + it * 8;
      dst[(size_t)c * K + k0 + ck] = (_Float16)tile[ci + it * 8][ck];  // coalesced in k
    }
  } else if (bid < 176) {  // attn rows for layer b: bt rows 256..288
    int b = bid - 172;
    _Float16* dstL = bt + (size_t)b * 288 * 128;
    for (int idx = threadIdx.x; idx < 32 * 128; idx += 256) {
      int c = 256 + (idx >> 7), k = idx & 127;
      int sub = c - 256, blk = sub >> 3, h = sub & 7;
      int r = blk >> 1;
      const float* attn = (blk & 1) ? gar : gal;
      const float* W = gfc + (size_t)(2 * b + r) * 16384;
      const float* av = attn + (size_t)(2 * b + r) * 128 + h * 16;
      float s = 0.f;
#pragma unroll
      for (int d = 0; d < 16; ++d) s += W[k * 128 + h * 16 + d] * av[d];
      dstL[c * 128 + k] = (_Float16)s;
    }
  } else if (bid == 176) {  // zero elmax + stats
    if (threadIdx.x < 64) elmax[threadIdx.x] = 0u;
    for (int i = threadIdx.x; i < 1024; i += 256) statsz[i] = 0.f;
  } else {  // bhist: 128 blocks
    int j = bid - 177;
    int r = j >> 6, blk = j & 63;
    __shared__ int bins[NBIN];
    for (int i = threadIdx.x; i < NBIN; i += 256) bins[i] = 0;
    __syncthreads();
    const int* d = dstIdx + (size_t)r * EE;
    int e0 = blk * EPB;
    for (int e = e0 + threadIdx.x; e < e0 + EPB; e += 256)
      atomicAdd(&bins[d[e] >> 8], 1);
    __syncthreads();
    for (int i = threadIdx.x; i < NBIN; i += 256)
      bcnt[(size_t)(r * NBIN + i) * NBLK + blk] = bins[i];
  }
}

// ---------------------------------------------------------------------------
// scanA (kept): chunk-local exclusive scan in-place + chunk totals.
// R19: scanB is folded into bscat/bfin (each re-derives the 98-chunk offset
// scan from `totals` in LDS) -> one fewer launch.
// ---------------------------------------------------------------------------
__global__ __launch_bounds__(256)
void scanA_k(int* __restrict__ bcnt, int* __restrict__ totals) {
  __shared__ int sh[256];
  int b = blockIdx.x, t = threadIdx.x;
  int idx = b * 256 + t;
  int v = bcnt[idx];
  sh[t] = v;
  __syncthreads();
#pragma unroll
  for (int off = 1; off < 256; off <<= 1) {
    int tv = (t >= off) ? sh[t - off] : 0;
    __syncthreads();
    sh[t] += tv;
    __syncthreads();
  }
  bcnt[idx] = sh[t] - v;               // exclusive within chunk
  if (t == 255) totals[b] = sh[t];     // inclusive total
}

// in-block exclusive scan of totals[0..SCHUNK) -> boffs (LDS), all 256 threads
__device__ __forceinline__ void chunk_offsets(const int* __restrict__ totals,
                                              int* __restrict__ boffs) {
  __shared__ int sh[256];
  int t = threadIdx.x;
  int v = (t < SCHUNK) ? totals[t] : 0;
  sh[t] = v;
  __syncthreads();
#pragma unroll
  for (int off = 1; off < 256; off <<= 1) {
    int tv = (t >= off) ? sh[t - off] : 0;
    __syncthreads();
    sh[t] += tv;
    __syncthreads();
  }
  if (t < SCHUNK) boffs[t] = sh[t] - v;  // exclusive
  __syncthreads();
}

__global__ __launch_bounds__(256)
void bscat_k(const int* __restrict__ src, const int* __restrict__ dst,
             const int* __restrict__ bcnt, const int* __restrict__ totals,
             unsigned* __restrict__ packed) {
  int r = blockIdx.y, blk = blockIdx.x;
  __shared__ int base[NBIN];
  __shared__ int boffs[SCHUNK];
  chunk_offsets(totals, boffs);
  for (int i = threadIdx.x; i < NBIN; i += 256) {
    int idx = (r * NBIN + i) * NBLK + blk;
    base[i] = bcnt[idx] + boffs[idx >> 8];
  }
  __syncthreads();
  const int* d = dst + (size_t)r * EE;
  const int* s = src + (size_t)r * EE;
  int e0 = blk * EPB;
  for (int e = e0 + threadIdx.x; e < e0 + EPB; e += 256) {
    int dd = d[e];
    int pos = atomicAdd(&base[dd >> 8], 1);
    packed[pos] = (unsigned)s[e] | ((unsigned)dd << 16);
  }
}

__global__ __launch_bounds__(256)
void bfin_k(const unsigned* __restrict__ packed, const int* __restrict__ bcnt,
            const int* __restrict__ totals, int* __restrict__ rowptr,
            unsigned short* __restrict__ csr) {
  int f = blockIdx.x;  // 0 .. 2*NBIN-1
  int r = f / NBIN, b = f % NBIN;
  __shared__ int boffs[SCHUNK];
  chunk_offsets(totals, boffs);
  __shared__ int deg[256], pref[256], pos[256];
  int start = bcnt[(size_t)f * NBLK] + boffs[(f * NBLK) >> 8];
  int end = (f + 1 < 2 * NBIN)
                ? (bcnt[(size_t)(f + 1) * NBLK] + boffs[((f + 1) * NBLK) >> 8])
                : 2 * EE;
  deg[threadIdx.x] = 0;
  __syncthreads();
  for (int e = start + threadIdx.x; e < end; e += 256)
    atomicAdd(&deg[(packed[e] >> 16) & 255], 1);
  __syncthreads();
  int v = deg[threadIdx.x];
  pref[threadIdx.x] = v;
  __syncthreads();
#pragma unroll
  for (int off = 1; off < 256; off <<= 1) {
    int tv = (threadIdx.x >= off) ? pref[threadIdx.x - off] : 0;
    __syncthreads();
    pref[threadIdx.x] += tv;
    __syncthreads();
  }
  int excl = pref[threadIdx.x] - v;
  int node = b * 256 + threadIdx.x;
  if (node < NN) rowptr[r * (NN + 1) + node] = start - r * EE + excl;
  if (node == NN) rowptr[r * (NN + 1) + NN] = EE;
  pos[threadIdx.x] = start + excl;
  __syncthreads();
  for (int e = start + threadIdx.x; e < end; e += 256) {
    unsigned pk = packed[e];
    int local = (pk >> 16) & 255;
    int p = atomicAdd(&pos[local], 1);
    csr[p] = (unsigned short)(pk & 0xffffu);
  }
}

// ---------------------------------------------------------------------------
// GAT aggregate — R19: software-pipelined index chain. The per-chunk serial
// dependency csr->el->exp is broken by prefetching `so` at distance 2 and
// `el` at distance 1; the feature-gather address stream is byte-identical
// to the proven R15/R18 form (230MB fetch). Prefetched values beyond `len`
// are clamped-safe and never consumed.
// ---------------------------------------------------------------------------
__global__ __launch_bounds__(256)
void gat_agg_k(const __half2* __restrict__ f0, const __half2* __restrict__ f1,
               const _Float16* __restrict__ el0h, const float* __restrict__ er0,
               const _Float16* __restrict__ el1h, const float* __restrict__ er1,
               const int* __restrict__ rowptr, const unsigned short* __restrict__ csr,
               const float* __restrict__ b0, const float* __restrict__ b1,
               const unsigned* __restrict__ elmax,
               _Float16* __restrict__ h1h) {
  int n = blockIdx.x * 4 + (threadIdx.x >> 6);
  if (n >= NN) return;
  int lane = threadIdx.x & 63;
  int head = lane >> 3, eslot = lane & 7;
  float er0h = er0[(size_t)n * 8 + head];
  float er1h = er1[(size_t)n * 8 + head];
  float bnd0 = fdec(elmax[head]) + er0h;       bnd0 = fmaxf(bnd0, 0.2f * bnd0);
  float bnd1 = fdec(elmax[8 + head]) + er1h;   bnd1 = fmaxf(bnd1, 0.2f * bnd1);
  int beg0 = rowptr[n], end0 = rowptr[n + 1];
  const int* rp1 = rowptr + (NN + 1);
  int beg1 = rp1[n], end1 = rp1[n + 1];
  const unsigned short* csr1 = csr + EE;
  int len = max(end0 - beg0, end1 - beg1);

#define CLAMP0(X) max(min((X), end0 - 1), 0)
#define CLAMP1(X) max(min((X), end1 - 1), 0)
  // pipeline prologue: so for chunks 0 and 8; el for chunk 0
  int sA0 = (int)csr[CLAMP0(beg0 + eslot)];
  int sA1 = (int)csr1[CLAMP1(beg1 + eslot)];
  int sB0 = (int)csr[CLAMP0(beg0 + 8 + eslot)];
  int sB1 = (int)csr1[CLAMP1(beg1 + 8 + eslot)];
  float evA0 = (float)el0h[(size_t)sA0 * 8 + head];
  float evA1 = (float)el1h[(size_t)sA1 * 8 + head];

  float ls0 = 0.f, a00 = 0.f, a01 = 0.f;
  float ls1 = 0.f, a10 = 0.f, a11 = 0.f;
  for (int t = 0; t < len; t += 8) {
    // issue so(t+16) + el(t+8) (uses sB, issued one iteration ago)
    int sC0 = (int)csr[CLAMP0(beg0 + t + 16 + eslot)];
    int sC1 = (int)csr1[CLAMP1(beg1 + t + 16 + eslot)];
    float evB0 = (float)el0h[(size_t)sB0 * 8 + head];
    float evB1 = (float)el1h[(size_t)sB1 * 8 + head];

    // gathers for chunk t via swizzle-broadcast of sA
    __half2 g0[8], g1[8];
#define LDJ(J)                                                          \
    {                                                                   \
      int sj0 = __builtin_amdgcn_ds_swizzle(sA0, ((J) << 5) | 0x18);    \
      int sj1 = __builtin_amdgcn_ds_swizzle(sA1, ((J) << 5) | 0x18);    \
      g0[J] = f0[(size_t)sj0 * 64 + lane];                              \
      g1[J] = f1[(size_t)sj1 * 64 + lane];                              \
    }
    LDJ(0) LDJ(1) LDJ(2) LDJ(3) LDJ(4) LDJ(5) LDJ(6) LDJ(7)
#undef LDJ

    // per-lane attention weight for chunk t (el already in registers)
    int i0 = beg0 + t + eslot, i1 = beg1 + t + eslot;
    float e0 = evA0 + er0h; e0 = fmaxf(e0, 0.2f * e0);
    float p0 = __expf(e0 - bnd0);
    p0 = (i0 < end0) ? p0 : 0.f;
    float e1 = evA1 + er1h; e1 = fmaxf(e1, 0.2f * e1);
    float p1 = __expf(e1 - bnd1);
    p1 = (i1 < end1) ? p1 : 0.f;
    ls0 += p0; ls1 += p1;            // own slot only; reduced after loop

    // broadcast p within each 8-lane head group via immediate swizzle
#define ACCJ(J)                                                     \
    {                                                               \
      float pj0 = ds_swz<((J) << 5) | 0x18>(p0);                    \
      float pj1 = ds_swz<((J) << 5) | 0x18>(p1);                    \
      a00 = fmaf(__low2float(g0[J]), pj0, a00);                     \
      a01 = fmaf(__high2float(g0[J]), pj0, a01);                    \
      a10 = fmaf(__low2float(g1[J]), pj1, a10);                     \
      a11 = fmaf(__high2float(g1[J]), pj1, a11);                    \
    }
    ACCJ(0) ACCJ(1) ACCJ(2) ACCJ(3) ACCJ(4) ACCJ(5) ACCJ(6) ACCJ(7)
#undef ACCJ

    // rotate pipeline registers
    sA0 = sB0; sA1 = sB1; sB0 = sC0; sB1 = sC1;
    evA0 = evB0; evA1 = evB1;
  }
#undef CLAMP0
#undef CLAMP1

  // softmax denominator: xor-reduce within each 8-lane head group
  ls0 += ds_swz<(1 << 10) | 0x1F>(ls0);
  ls0 += ds_swz<(2 << 10) | 0x1F>(ls0);
  ls0 += ds_swz<(4 << 10) | 0x1F>(ls0);
  ls1 += ds_swz<(1 << 10) | 0x1F>(ls1);
  ls1 += ds_swz<(2 << 10) | 0x1F>(ls1);
  ls1 += ds_swz<(4 << 10) | 0x1F>(ls1);

  float inv0 = (ls0 > 0.f) ? 1.f / ls0 : 0.f;  // isolated node -> rst = 0
  float inv1 = (ls1 > 0.f) ? 1.f / ls1 : 0.f;
  float t0 = a00 * inv0 + a10 * inv1 + b0[lane * 2] + b1[lane * 2];
  float t1 = a01 * inv0 + a11 * inv1 + b0[lane * 2 + 1] + b1[lane * 2 + 1];
  t0 = (t0 > 0.f) ? t0 : 0.01f * t0;           // leaky_relu 0.01
  t1 = (t1 > 0.f) ? t1 : 0.01f * t1;
  __half2* hh = (__half2*)h1h + (size_t)n * 64 + lane;
  float2 h = __half22float2(*hh);
  h.x += t0; h.y += t1;
  *hh = __floats2half2_rn(h.x, h.y);
}

// ---------------------------------------------------------------------------
extern "C" void kernel_launch(void* const* d_in, const int* in_sizes, int n_in,
                              void* d_out, int out_size, void* d_ws,
                              size_t ws_size, hipStream_t stream) {
  const float* inputs = (const float*)d_in[0];
  const int* src = (const int*)d_in[1];
  const int* dst = (const int*)d_in[2];
  const float* ew1 = (const float*)d_in[3];
  const float* eg = (const float*)d_in[4];
  const float* eb = (const float*)d_in[5];
  const float* ew2 = (const float*)d_in[6];
  const float* gfc = (const float*)d_in[7];
  const float* gal = (const float*)d_in[8];
  const float* gar = (const float*)d_in[9];
  const float* gb = (const float*)d_in[10];
  const float* dw1 = (const float*)d_in[11];
  const float* dg = (const float*)d_in[12];
  const float* db = (const float*)d_in[13];
  const float* dw2 = (const float*)d_in[14];
  float* out = (float*)d_out;

  // ---- workspace layout (~56 MB) ----
  char* p = (char*)d_ws;
  // region A (25.6MB): ybuf_h (MLP phases) | feat0h+feat1h (GAT phase)
  _Float16* feat0h = (_Float16*)p;
  _Float16* feat1h = feat0h + (size_t)NN * 128;
  _Float16* ybuf_h = feat0h;        // alias: MLP and GAT phases don't overlap
  p += (size_t)NN * 128 * 4;
  _Float16* h1h = (_Float16*)p;     p += (size_t)NN * 128 * 2;   // 12.8MB
  _Float16* el0h = (_Float16*)p;    p += (size_t)NN * NHEAD * 2;
  float* er0 = (float*)p;           p += (size_t)NN * NHEAD * 4;
  _Float16* el1h = (_Float16*)p;    p += (size_t)NN * NHEAD * 2;
  float* er1 = (float*)p;           p += (size_t)NN * NHEAD * 4;
  float* stats = (float*)p;         p += 1024 * 4;  // stats_e | stats_d
  float* stats_e = stats;
  float* stats_d = stats + 512;
  _Float16* ew1t = (_Float16*)p;    p += (size_t)64 * 128 * 2;
  _Float16* ew2t = (_Float16*)p;    p += (size_t)128 * 128 * 2;
  _Float16* dw1t = (_Float16*)p;    p += (size_t)128 * 128 * 2;
  _Float16* dw2t = (_Float16*)p;    p += (size_t)32 * 128 * 2;
  _Float16* bt = (_Float16*)p;      p += (size_t)4 * 288 * 128 * 2;
  int* rowptr = (int*)p;            p += (size_t)2 * (NN + 1) * 4;
  unsigned short* csr = (unsigned short*)p;   p += (size_t)2 * EE * 2;
  unsigned* packed = (unsigned*)p;  p += (size_t)2 * EE * 4;    // 6.4MB
  int* bcnt = (int*)p;              p += (size_t)SCT * 4;       // 100KB
  int* totals = (int*)p;            p += 128 * 4;
  unsigned* elmaxAll = (unsigned*)p;  // 64 uints (4 layers x 16)

  const int GB = (NN + 127) / 128;  // 391

  // ---- build (weights + zero + bhist merged) + parallel-scan CSR ----
  build_k<<<305, 256, 0, stream>>>(ew1, ew2, dw1, dw2, gfc, gal, gar,
                                   ew1t, ew2t, dw1t, dw2t, bt, stats, elmaxAll,
                                   dst, bcnt);
  scanA_k<<<SCHUNK, 256, 0, stream>>>(bcnt, totals);
  bscat_k<<<dim3(NBLK, 2), 256, 0, stream>>>(src, dst, bcnt, totals, packed);
  bfin_k<<<2 * NBIN, 256, 0, stream>>>(packed, bcnt, totals, rowptr, csr);

  // ---- embed MLP: y=x@w1 (fp16 store, +stats); h1h=relu(bn(y))@w2+relu(bn(y))
  mfma_gemm_k<64, 128, float, false, false, true, true, false>
      <<<GB, 256, 0, stream>>>(inputs, ew1t, nullptr, nullptr, nullptr,
                               stats_e, nullptr, ybuf_h, nullptr, NN);
  mfma_gemm_k<128, 128, _Float16, true, true, false, true, false>
      <<<GB, 256, 0, stream>>>(ybuf_h, ew2t, stats_e, eg, eb, nullptr,
                               ybuf_h, h1h, nullptr, NN);

  // ---- 4 GAT layers: merged GEMM(+el/er/elmax) then aggregate ----
  for (int l = 0; l < 4; ++l) {
    unsigned* elm = elmaxAll + l * 16;
    feat_gemm_k<<<GB, 256, 0, stream>>>(
        h1h, bt + (size_t)l * 288 * 128, feat0h, feat1h,
        el0h, er0, el1h, er1, elm, NN);
    gat_agg_k<<<(NN + 3) / 4, 256, 0, stream>>>(
        (const __half2*)feat0h, (const __half2*)feat1h, el0h, er0, el1h, er1,
        rowptr, csr, gb + (size_t)(l * 2 + 0) * 128,
        gb + (size_t)(l * 2 + 1) * 128, elm, h1h);
  }

  // ---- decision MLP: y = h1h@dw1 (fp16 store, +stats); out = relu(bn(y))@dw2
  mfma_gemm_k<128, 128, _Float16, false, false, true, true, false>
      <<<GB, 256, 0, stream>>>(h1h, dw1t, nullptr, nullptr, nullptr, stats_d,
                               nullptr, ybuf_h, nullptr, NN);
  mfma_gemm_k<128, 32, _Float16, true, false, false, false, true>
      <<<GB, 256, 0, stream>>>(ybuf_h, dw2t, stats_d, dg, db, nullptr,
                               nullptr, nullptr, out, NN);
}

// Round 9
// 619.767 us; speedup vs baseline: 1.0187x; 1.0187x over previous
//
#include <hip/hip_runtime.h>
#include <hip/hip_fp16.h>
#include <math.h>

#define NN 50000
#define EE 800000
#define NHEAD 8
#define BN_EPS 1e-5f
#define NBIN 196            // ceil(NN/256) coarse buckets (dst>>8)
#define NBLK 64             // edge blocks per relation
#define EPB (EE / NBLK)     // 12500 edges per block (exact)
#define SCT (2 * NBIN * NBLK)  // 25088 scan elements = 98*256 exact
#define SCHUNK 98           // SCT / 256

typedef _Float16 half8_t __attribute__((ext_vector_type(8)));
typedef float float4_t __attribute__((ext_vector_type(4)));

// monotone float<->uint encoding for atomicMax on signed floats
__device__ __forceinline__ unsigned fenc(float f) {
  unsigned u = __float_as_uint(f);
  return (u & 0x80000000u) ? ~u : (u | 0x80000000u);
}
__device__ __forceinline__ float fdec(unsigned k) {
  return (k & 0x80000000u) ? __uint_as_float(k & 0x7fffffffu)
                           : __uint_as_float(~k);
}

// bn scale/shift from raw sums (stats[c]=sum, stats[128+c]=sumsq)
__device__ __forceinline__ void bn_coef(const float* __restrict__ stats,
                                        const float* __restrict__ gamma,
                                        const float* __restrict__ beta,
                                        int c, float& sc, float& sh) {
  float mean = stats[c] * (1.f / NN);
  float var = fmaxf(stats[128 + c] * (1.f / NN) - mean * mean, 0.f);
  sc = gamma[c] * rsqrtf(var + BN_EPS);
  sh = beta[c] - mean * sc;
}

// static lane swizzle (BitMode): new_lane = ((lane & and) | or) ^ xor, per 32-half
template <int PAT>
__device__ __forceinline__ float ds_swz(float x) {
  return __int_as_float(__builtin_amdgcn_ds_swizzle(__float_as_int(x), PAT));
}

// ---------------------------------------------------------------------------
// MFMA GEMM for embed/decision MLPs — R18 structure (128-row blocks, LDS
// pre-reduced STATS -> one global atomicAdd set per block).
// ---------------------------------------------------------------------------
template <int KDIM, int NC, typename AT, bool ABN, bool RESIDBN, bool STATS,
          bool F16OUT, bool F32OUT>
__global__ __launch_bounds__(256)
void mfma_gemm_k(const AT* __restrict__ A, const _Float16* __restrict__ Bt,
                 const float* __restrict__ bn, const float* __restrict__ gamma,
                 const float* __restrict__ beta, float* __restrict__ statsOut,
                 const _Float16* __restrict__ residh, _Float16* __restrict__ Ch,
                 float* __restrict__ Cf, int M) {
  constexpr int NT = NC / 16;
  const int lane = threadIdx.x & 63, wave = threadIdx.x >> 6;
  const int q = lane >> 4, l16 = lane & 15;
  const int row0 = blockIdx.x * 128 + wave * 32;
  float4_t acc[2][NT];
#pragma unroll
  for (int i = 0; i < 2; ++i)
#pragma unroll
    for (int j = 0; j < NT; ++j) acc[i][j] = (float4_t){0.f, 0.f, 0.f, 0.f};

#pragma unroll
  for (int kk = 0; kk < KDIM / 32; ++kk) {
    float scv[8], shv[8];
    if constexpr (ABN) {
      int kb = kk * 32 + q * 8;
#pragma unroll
      for (int x = 0; x < 8; ++x) bn_coef(bn, gamma, beta, kb + x, scv[x], shv[x]);
    }
    half8_t a[2];
#pragma unroll
    for (int i = 0; i < 2; ++i) {
      int r = row0 + i * 16 + l16;
      r = (r < M) ? r : (M - 1);
      if constexpr (__is_same(AT, _Float16)) {
        half8_t hv = *(const half8_t*)(A + (size_t)r * KDIM + kk * 32 + q * 8);
        if constexpr (ABN) {
#pragma unroll
          for (int x = 0; x < 8; ++x)
            hv[x] = (_Float16)fmaxf((float)hv[x] * scv[x] + shv[x], 0.f);
        }
        a[i] = hv;
      } else {
        const float* ap = (const float*)A + (size_t)r * KDIM + kk * 32 + q * 8;
        float4 v0 = *(const float4*)ap, v1 = *(const float4*)(ap + 4);
        float t[8] = {v0.x, v0.y, v0.z, v0.w, v1.x, v1.y, v1.z, v1.w};
        if constexpr (ABN) {
#pragma unroll
          for (int x = 0; x < 8; ++x) t[x] = fmaxf(t[x] * scv[x] + shv[x], 0.f);
        }
        half8_t hv;
#pragma unroll
        for (int x = 0; x < 8; ++x) hv[x] = (_Float16)t[x];
        a[i] = hv;
      }
    }
#pragma unroll
    for (int j = 0; j < NT; ++j) {
      half8_t b = *(const half8_t*)(Bt + (size_t)(j * 16 + l16) * KDIM + kk * 32 + q * 8);
      acc[0][j] = __builtin_amdgcn_mfma_f32_16x16x32_f16(a[0], b, acc[0][j], 0, 0, 0);
      acc[1][j] = __builtin_amdgcn_mfma_f32_16x16x32_f16(a[1], b, acc[1][j], 0, 0, 0);
    }
  }

  float rsc[NT], rsh[NT];
  if constexpr (RESIDBN) {
#pragma unroll
    for (int j = 0; j < NT; ++j) bn_coef(bn, gamma, beta, j * 16 + l16, rsc[j], rsh[j]);
  }
#pragma unroll
  for (int i = 0; i < 2; ++i)
#pragma unroll
    for (int r = 0; r < 4; ++r) {
      int row = row0 + i * 16 + q * 4 + r;   // C/D: col=lane&15, row=q*4+reg
      if (row >= M) continue;
      float vv[NT];
#pragma unroll
      for (int j = 0; j < NT; ++j) {
        float v = acc[i][j][r];
        if constexpr (RESIDBN) {
          float rv = (float)residh[(size_t)row * NC + j * 16 + l16];
          v += fmaxf(rv * rsc[j] + rsh[j], 0.f);
        }
        vv[j] = v;
        if constexpr (F32OUT) Cf[(size_t)row * NC + j * 16 + l16] = v;
      }
      if constexpr (F16OUT) {
        // pair columns across lane pairs l16^1 (full-line packed __half2 stores)
        const bool ev = (l16 & 1) == 0;
#pragma unroll
        for (int jp = 0; jp < NT / 2; ++jp) {
          float a_ = vv[2 * jp], b_ = vv[2 * jp + 1];
          float an = ds_swz<(1 << 10) | 0x1F>(a_);
          float bn_ = ds_swz<(1 << 10) | 0x1F>(b_);
          float lo = ev ? a_ : bn_;
          float hi = ev ? an : b_;
          int jj = ev ? 2 * jp : 2 * jp + 1;
          __half2 hv = __floats2half2_rn(lo, hi);
          ((__half2*)Ch)[((size_t)row * NC + jj * 16 + (l16 & ~1)) >> 1] = hv;
        }
      }
    }

  if constexpr (STATS) {
    static_assert(!STATS || NT == 8, "stats layout assumes NC=128");
    __shared__ float reds[256];
    reds[threadIdx.x] = 0.f;
    __syncthreads();
    float sc_[NT], sq_[NT];
#pragma unroll
    for (int j = 0; j < NT; ++j) {
      float s = 0.f, qq = 0.f;
#pragma unroll
      for (int i = 0; i < 2; ++i)
#pragma unroll
        for (int r = 0; r < 4; ++r) {
          int row = row0 + i * 16 + q * 4 + r;
          float x = (row < M) ? acc[i][j][r] : 0.f;
          s += x; qq += x * x;
        }
      sc_[j] = s; sq_[j] = qq;
    }
#pragma unroll
    for (int j = 0; j < NT; ++j) {
      sc_[j] += __shfl_xor(sc_[j], 16, 64);
      sq_[j] += __shfl_xor(sq_[j], 16, 64);
      sc_[j] += __shfl_xor(sc_[j], 32, 64);
      sq_[j] += __shfl_xor(sq_[j], 32, 64);
    }
    if (lane < 16) {
#pragma unroll
      for (int j = 0; j < NT; ++j) {
        atomicAdd(&reds[j * 16 + l16], sc_[j]);        // LDS pre-reduction
        atomicAdd(&reds[128 + j * 16 + l16], sq_[j]);
      }
    }
    __syncthreads();
    atomicAdd(&statsOut[threadIdx.x], reds[threadIdx.x]);  // 1 set / block
  }
}

// ---------------------------------------------------------------------------
// Merged per-layer GAT GEMM, NC=288 — R18 structure (unchanged).
// ---------------------------------------------------------------------------
__global__ __launch_bounds__(256)
void feat_gemm_k(const _Float16* __restrict__ A, const _Float16* __restrict__ Bt,
                 _Float16* __restrict__ feat0, _Float16* __restrict__ feat1,
                 _Float16* __restrict__ el0h, float* __restrict__ er0,
                 _Float16* __restrict__ el1h, float* __restrict__ er1,
                 unsigned* __restrict__ elmax, int M) {
  constexpr int NT = 18;
  const int lane = threadIdx.x & 63, wave = threadIdx.x >> 6;
  const int q = lane >> 4, l16 = lane & 15;
  const int row0 = blockIdx.x * 128 + wave * 32;
  __shared__ unsigned redm[16];
  if (threadIdx.x < 16) redm[threadIdx.x] = 0u;
  float4_t acc[2][NT];
#pragma unroll
  for (int i = 0; i < 2; ++i)
#pragma unroll
    for (int j = 0; j < NT; ++j) acc[i][j] = (float4_t){0.f, 0.f, 0.f, 0.f};

#pragma unroll
  for (int kk = 0; kk < 4; ++kk) {
    half8_t a[2];
#pragma unroll
    for (int i = 0; i < 2; ++i) {
      int r = row0 + i * 16 + l16;
      r = (r < M) ? r : (M - 1);
      a[i] = *(const half8_t*)(A + (size_t)r * 128 + kk * 32 + q * 8);
    }
#pragma unroll
    for (int j = 0; j < NT; ++j) {
      half8_t b = *(const half8_t*)(Bt + (size_t)(j * 16 + l16) * 128 + kk * 32 + q * 8);
      acc[0][j] = __builtin_amdgcn_mfma_f32_16x16x32_f16(a[0], b, acc[0][j], 0, 0, 0);
      acc[1][j] = __builtin_amdgcn_mfma_f32_16x16x32_f16(a[1], b, acc[1][j], 0, 0, 0);
    }
  }

#pragma unroll
  for (int i = 0; i < 2; ++i)
#pragma unroll
    for (int r = 0; r < 4; ++r) {
      int row = row0 + i * 16 + q * 4 + r;
      if (row >= M) continue;
      const bool ev = (l16 & 1) == 0;
#pragma unroll
      for (int jp = 0; jp < 8; ++jp) {     // pairs (2jp, 2jp+1); no feat0/1 straddle
        float a_ = acc[i][2 * jp][r], b_ = acc[i][2 * jp + 1][r];
        float an = ds_swz<(1 << 10) | 0x1F>(a_);
        float bn_ = ds_swz<(1 << 10) | 0x1F>(b_);
        float lo = ev ? a_ : bn_;
        float hi = ev ? an : b_;
        int jj = ev ? 2 * jp : 2 * jp + 1;
        __half2 hv = __floats2half2_rn(lo, hi);
        _Float16* fb = (jj < 8) ? feat0 : feat1;
        int colbase = (jj < 8) ? jj * 16 : (jj - 8) * 16;
        ((__half2*)fb)[((size_t)row * 128 + colbase + (l16 & ~1)) >> 1] = hv;
      }
      {
        float v = acc[i][16][r];
        if (l16 < 8) el0h[(size_t)row * 8 + l16] = (_Float16)v;
        else         er0[(size_t)row * 8 + (l16 - 8)] = v;
        v = acc[i][17][r];
        if (l16 < 8) el1h[(size_t)row * 8 + l16] = (_Float16)v;
        else         er1[(size_t)row * 8 + (l16 - 8)] = v;
      }
    }

  float m0 = -1e30f, m1 = -1e30f;
#pragma unroll
  for (int i = 0; i < 2; ++i)
#pragma unroll
    for (int r = 0; r < 4; ++r) {
      m0 = fmaxf(m0, acc[i][16][r]);
      m1 = fmaxf(m1, acc[i][17][r]);
    }
  m0 = fmaxf(m0, __shfl_xor(m0, 16, 64)); m0 = fmaxf(m0, __shfl_xor(m0, 32, 64));
  m1 = fmaxf(m1, __shfl_xor(m1, 16, 64)); m1 = fmaxf(m1, __shfl_xor(m1, 32, 64));
  __syncthreads();                       // redm init visible to all waves
  if (q == 0 && l16 < 8) {
    atomicMax(&redm[l16], fenc(m0));     // LDS pre-reduction across waves
    atomicMax(&redm[8 + l16], fenc(m1));
  }
  __syncthreads();
  if (threadIdx.x < 16) atomicMax(&elmax[threadIdx.x], redm[threadIdx.x]);
}

// ---------------------------------------------------------------------------
// R20: embed-GEMM1 block body, runs INSIDE build_k (independent of the
// transpose jobs: builds its own fp16 B-tile in LDS from raw ew1, stride 72
// halves = 144B rows -> 16B-aligned, 2-way-bank-conflict-free ds_read_b128).
// Math identical to mfma_gemm_k<64,128,float,false,false,true,true,false>.
// ---------------------------------------------------------------------------
__device__ __forceinline__ void embed1_block(
    const float* __restrict__ A, const float* __restrict__ ew1,
    float* __restrict__ statsOut, _Float16* __restrict__ Ch, int gb, int M) {
  constexpr int NT = 8, BS = 72;  // B row stride in halves
  __shared__ _Float16 blds[128 * BS];
  __shared__ float reds[256];
  for (int L = threadIdx.x; L < 128 * 64; L += 256) {
    int c = L >> 6, k = L & 63;
    blds[c * BS + k] = (_Float16)ew1[k * 128 + c];   // Bt[c][k] = ew1[k][c]
  }
  reds[threadIdx.x] = 0.f;
  __syncthreads();

  const int lane = threadIdx.x & 63, wave = threadIdx.x >> 6;
  const int q = lane >> 4, l16 = lane & 15;
  const int row0 = gb * 128 + wave * 32;
  float4_t acc[2][NT];
#pragma unroll
  for (int i = 0; i < 2; ++i)
#pragma unroll
    for (int j = 0; j < NT; ++j) acc[i][j] = (float4_t){0.f, 0.f, 0.f, 0.f};

#pragma unroll
  for (int kk = 0; kk < 2; ++kk) {
    half8_t a[2];
#pragma unroll
    for (int i = 0; i < 2; ++i) {
      int r = row0 + i * 16 + l16;
      r = (r < M) ? r : (M - 1);
      const float* ap = A + (size_t)r * 64 + kk * 32 + q * 8;
      float4 v0 = *(const float4*)ap, v1 = *(const float4*)(ap + 4);
      float t[8] = {v0.x, v0.y, v0.z, v0.w, v1.x, v1.y, v1.z, v1.w};
      half8_t hv;
#pragma unroll
      for (int x = 0; x < 8; ++x) hv[x] = (_Float16)t[x];
      a[i] = hv;
    }
#pragma unroll
    for (int j = 0; j < NT; ++j) {
      half8_t b = *(const half8_t*)(blds + (size_t)(j * 16 + l16) * BS + kk * 32 + q * 8);
      acc[0][j] = __builtin_amdgcn_mfma_f32_16x16x32_f16(a[0], b, acc[0][j], 0, 0, 0);
      acc[1][j] = __builtin_amdgcn_mfma_f32_16x16x32_f16(a[1], b, acc[1][j], 0, 0, 0);
    }
  }

#pragma unroll
  for (int i = 0; i < 2; ++i)
#pragma unroll
    for (int r = 0; r < 4; ++r) {
      int row = row0 + i * 16 + q * 4 + r;
      if (row >= M) continue;
      float vv[NT];
#pragma unroll
      for (int j = 0; j < NT; ++j) vv[j] = acc[i][j][r];
      const bool ev = (l16 & 1) == 0;
#pragma unroll
      for (int jp = 0; jp < NT / 2; ++jp) {
        float a_ = vv[2 * jp], b_ = vv[2 * jp + 1];
        float an = ds_swz<(1 << 10) | 0x1F>(a_);
        float bn_ = ds_swz<(1 << 10) | 0x1F>(b_);
        float lo = ev ? a_ : bn_;
        float hi = ev ? an : b_;
        int jj = ev ? 2 * jp : 2 * jp + 1;
        __half2 hv = __floats2half2_rn(lo, hi);
        ((__half2*)Ch)[((size_t)row * 128 + jj * 16 + (l16 & ~1)) >> 1] = hv;
      }
    }

  {  // stats: LDS pre-reduction, one global atomicAdd set per block
    float sc_[NT], sq_[NT];
#pragma unroll
    for (int j = 0; j < NT; ++j) {
      float s = 0.f, qq = 0.f;
#pragma unroll
      for (int i = 0; i < 2; ++i)
#pragma unroll
        for (int r = 0; r < 4; ++r) {
          int row = row0 + i * 16 + q * 4 + r;
          float x = (row < M) ? acc[i][j][r] : 0.f;
          s += x; qq += x * x;
        }
      sc_[j] = s; sq_[j] = qq;
    }
#pragma unroll
    for (int j = 0; j < NT; ++j) {
      sc_[j] += __shfl_xor(sc_[j], 16, 64);
      sq_[j] += __shfl_xor(sq_[j], 16, 64);
      sc_[j] += __shfl_xor(sc_[j], 32, 64);
      sq_[j] += __shfl_xor(sq_[j], 32, 64);
    }
    if (lane < 16) {
#pragma unroll
      for (int j = 0; j < NT; ++j) {
        atomicAdd(&reds[j * 16 + l16], sc_[j]);
        atomicAdd(&reds[128 + j * 16 + l16], sq_[j]);
      }
    }
    __syncthreads();
    atomicAdd(&statsOut[threadIdx.x], reds[threadIdx.x]);
  }
}

// ---------------------------------------------------------------------------
// R20 build: tiled transposes + bhist + embed-GEMM1 merged. Grid = 696:
//   0..171   transpose jobs; 172..175 attn rows; 176 zero elmax (stats is
//   zeroed by hipMemsetAsync BEFORE this launch — in-kernel zeroing would
//   race with GEMM1's atomics); 177..304 bhist; 305..695 embed-GEMM1.
// ---------------------------------------------------------------------------
__global__ __launch_bounds__(256)
void build_k(const float* __restrict__ ew1, const float* __restrict__ ew2,
             const float* __restrict__ dw1, const float* __restrict__ dw2,
             const float* __restrict__ gfc, const float* __restrict__ gal,
             const float* __restrict__ gar, _Float16* __restrict__ ew1t,
             _Float16* __restrict__ ew2t, _Float16* __restrict__ dw1t,
             _Float16* __restrict__ dw2t, _Float16* __restrict__ bt,
             unsigned* __restrict__ elmax,
             const int* __restrict__ dstIdx, int* __restrict__ bcnt,
             const float* __restrict__ inputs, float* __restrict__ stats_e,
             _Float16* __restrict__ ybuf_h) {
  const int bid = blockIdx.x;

  if (bid < 172) {  // tiled transpose jobs
    const float* src; _Float16* dst; int K, N, kt, ct;
    if (bid < 8)       { src = ew1; dst = ew1t; K = 64;  N = 128; int t = bid;      kt = t >> 2; ct = t & 3; }
    else if (bid < 24) { src = ew2; dst = ew2t; K = 128; N = 128; int t = bid - 8;  kt = t >> 2; ct = t & 3; }
    else if (bid < 40) { src = dw1; dst = dw1t; K = 128; N = 128; int t = bid - 24; kt = t >> 2; ct = t & 3; }
    else if (bid < 44) { src = dw2; dst = dw2t; K = 128; N = 32;  int t = bid - 40; kt = t;      ct = 0;     }
    else {
      int idx = bid - 44;          // 8 mats x 16 tiles
      int mat = idx >> 4, t = idx & 15;
      int b = mat >> 1, r = mat & 1;
      src = gfc + (size_t)(2 * b + r) * 16384;
      dst = bt + (size_t)b * 288 * 128 + (size_t)r * 128 * 128;
      K = 128; N = 128; kt = t >> 2; ct = t & 3;
    }
    __shared__ float tile[32][33];
    int k0 = kt * 32, c0 = ct * 32;
    int tk = threadIdx.x >> 5, tc = threadIdx.x & 31;  // 8 k-rows x 32 c-cols
#pragma unroll
    for (int it = 0; it < 4; ++it) {
      int k = k0 + tk + it * 8;
      tile[tc][tk + it * 8] = src[(size_t)k * N + c0 + tc];  // coalesced in c
    }
    __syncthreads();
    int ci = threadIdx.x >> 5, ck = threadIdx.x & 31;  // 8 c-rows x 32 k-cols
#pragma unroll
    for (int it = 0; it < 4; ++it) {
      int c = c0 + ci + it * 8;
      dst[(size_t)c * K + k0 + ck] = (_Float16)tile[ci + it * 8][ck];  // coalesced in k
    }
  } else if (bid < 176) {  // attn rows for layer b: bt rows 256..288
    int b = bid - 172;
    _Float16* dstL = bt + (size_t)b * 288 * 128;
    for (int idx = threadIdx.x; idx < 32 * 128; idx += 256) {
      int c = 256 + (idx >> 7), k = idx & 127;
      int sub = c - 256, blk = sub >> 3, h = sub & 7;
      int r = blk >> 1;
      const float* attn = (blk & 1) ? gar : gal;
      const float* W = gfc + (size_t)(2 * b + r) * 16384;
      const float* av = attn + (size_t)(2 * b + r) * 128 + h * 16;
      float s = 0.f;
#pragma unroll
      for (int d = 0; d < 16; ++d) s += W[k * 128 + h * 16 + d] * av[d];
      dstL[c * 128 + k] = (_Float16)s;
    }
  } else if (bid == 176) {  // zero elmax (consumed only by later launches)
    if (threadIdx.x < 64) elmax[threadIdx.x] = 0u;
  } else if (bid < 305) {  // bhist: 128 blocks
    int j = bid - 177;
    int r = j >> 6, blk = j & 63;
    __shared__ int bins[NBIN];
    for (int i = threadIdx.x; i < NBIN; i += 256) bins[i] = 0;
    __syncthreads();
    const int* d = dstIdx + (size_t)r * EE;
    int e0 = blk * EPB;
    for (int e = e0 + threadIdx.x; e < e0 + EPB; e += 256)
      atomicAdd(&bins[d[e] >> 8], 1);
    __syncthreads();
    for (int i = threadIdx.x; i < NBIN; i += 256)
      bcnt[(size_t)(r * NBIN + i) * NBLK + blk] = bins[i];
  } else {  // embed-GEMM1: 391 blocks
    embed1_block(inputs, ew1, stats_e, ybuf_h, bid - 305, NN);
  }
}

// ---------------------------------------------------------------------------
// scanA: chunk-local exclusive scan in-place + chunk totals. scanB folded
// into bscat/bfin via chunk_offsets (R19 form, kept).
// ---------------------------------------------------------------------------
__global__ __launch_bounds__(256)
void scanA_k(int* __restrict__ bcnt, int* __restrict__ totals) {
  __shared__ int sh[256];
  int b = blockIdx.x, t = threadIdx.x;
  int idx = b * 256 + t;
  int v = bcnt[idx];
  sh[t] = v;
  __syncthreads();
#pragma unroll
  for (int off = 1; off < 256; off <<= 1) {
    int tv = (t >= off) ? sh[t - off] : 0;
    __syncthreads();
    sh[t] += tv;
    __syncthreads();
  }
  bcnt[idx] = sh[t] - v;               // exclusive within chunk
  if (t == 255) totals[b] = sh[t];     // inclusive total
}

// in-block exclusive scan of totals[0..SCHUNK) -> boffs (LDS), all 256 threads
__device__ __forceinline__ void chunk_offsets(const int* __restrict__ totals,
                                              int* __restrict__ boffs) {
  __shared__ int sh[256];
  int t = threadIdx.x;
  int v = (t < SCHUNK) ? totals[t] : 0;
  sh[t] = v;
  __syncthreads();
#pragma unroll
  for (int off = 1; off < 256; off <<= 1) {
    int tv = (t >= off) ? sh[t - off] : 0;
    __syncthreads();
    sh[t] += tv;
    __syncthreads();
  }
  if (t < SCHUNK) boffs[t] = sh[t] - v;  // exclusive
  __syncthreads();
}

__global__ __launch_bounds__(256)
void bscat_k(const int* __restrict__ src, const int* __restrict__ dst,
             const int* __restrict__ bcnt, const int* __restrict__ totals,
             unsigned* __restrict__ packed) {
  int r = blockIdx.y, blk = blockIdx.x;
  __shared__ int base[NBIN];
  __shared__ int boffs[SCHUNK];
  chunk_offsets(totals, boffs);
  for (int i = threadIdx.x; i < NBIN; i += 256) {
    int idx = (r * NBIN + i) * NBLK + blk;
    base[i] = bcnt[idx] + boffs[idx >> 8];
  }
  __syncthreads();
  const int* d = dst + (size_t)r * EE;
  const int* s = src + (size_t)r * EE;
  int e0 = blk * EPB;
  for (int e = e0 + threadIdx.x; e < e0 + EPB; e += 256) {
    int dd = d[e];
    int pos = atomicAdd(&base[dd >> 8], 1);
    packed[pos] = (unsigned)s[e] | ((unsigned)dd << 16);
  }
}

__global__ __launch_bounds__(256)
void bfin_k(const unsigned* __restrict__ packed, const int* __restrict__ bcnt,
            const int* __restrict__ totals, int* __restrict__ rowptr,
            unsigned short* __restrict__ csr) {
  int f = blockIdx.x;  // 0 .. 2*NBIN-1
  int r = f / NBIN, b = f % NBIN;
  __shared__ int boffs[SCHUNK];
  chunk_offsets(totals, boffs);
  __shared__ int deg[256], pref[256], pos[256];
  int start = bcnt[(size_t)f * NBLK] + boffs[(f * NBLK) >> 8];
  int end = (f + 1 < 2 * NBIN)
                ? (bcnt[(size_t)(f + 1) * NBLK] + boffs[((f + 1) * NBLK) >> 8])
                : 2 * EE;
  deg[threadIdx.x] = 0;
  __syncthreads();
  for (int e = start + threadIdx.x; e < end; e += 256)
    atomicAdd(&deg[(packed[e] >> 16) & 255], 1);
  __syncthreads();
  int v = deg[threadIdx.x];
  pref[threadIdx.x] = v;
  __syncthreads();
#pragma unroll
  for (int off = 1; off < 256; off <<= 1) {
    int tv = (threadIdx.x >= off) ? pref[threadIdx.x - off] : 0;
    __syncthreads();
    pref[threadIdx.x] += tv;
    __syncthreads();
  }
  int excl = pref[threadIdx.x] - v;
  int node = b * 256 + threadIdx.x;
  if (node < NN) rowptr[r * (NN + 1) + node] = start - r * EE + excl;
  if (node == NN) rowptr[r * (NN + 1) + NN] = EE;
  pos[threadIdx.x] = start + excl;
  __syncthreads();
  for (int e = start + threadIdx.x; e < end; e += 256) {
    unsigned pk = packed[e];
    int local = (pk >> 16) & 255;
    int p = atomicAdd(&pos[local], 1);
    csr[p] = (unsigned short)(pk & 0xffffu);
  }
}

// ---------------------------------------------------------------------------
// GAT aggregate — reverted to the R18 kernel verbatim (proven 70.6 µs /
// 230 MB / 3.50 TB/s; R19's pipelined variant regressed to 73.0 µs).
// ---------------------------------------------------------------------------
__global__ __launch_bounds__(256)
void gat_agg_k(const __half2* __restrict__ f0, const __half2* __restrict__ f1,
               const _Float16* __restrict__ el0h, const float* __restrict__ er0,
               const _Float16* __restrict__ el1h, const float* __restrict__ er1,
               const int* __restrict__ rowptr, const unsigned short* __restrict__ csr,
               const float* __restrict__ b0, const float* __restrict__ b1,
               const unsigned* __restrict__ elmax,
               _Float16* __restrict__ h1h) {
  int n = blockIdx.x * 4 + (threadIdx.x >> 6);
  if (n >= NN) return;
  int lane = threadIdx.x & 63;
  int head = lane >> 3, eslot = lane & 7;
  float er0h = er0[(size_t)n * 8 + head];
  float er1h = er1[(size_t)n * 8 + head];
  float bnd0 = fdec(elmax[head]) + er0h;       bnd0 = fmaxf(bnd0, 0.2f * bnd0);
  float bnd1 = fdec(elmax[8 + head]) + er1h;   bnd1 = fmaxf(bnd1, 0.2f * bnd1);
  int beg0 = rowptr[n], end0 = rowptr[n + 1];
  const int* rp1 = rowptr + (NN + 1);
  int beg1 = rp1[n], end1 = rp1[n + 1];
  const unsigned short* csr1 = csr + EE;
  int len = max(end0 - beg0, end1 - beg1);

  float ls0 = 0.f, a00 = 0.f, a01 = 0.f;
  float ls1 = 0.f, a10 = 0.f, a11 = 0.f;
  for (int t = 0; t < len; t += 8) {
    int t0 = beg0 + t, t1 = beg1 + t;
    int so0 = (int)csr[max(min(t0 + eslot, end0 - 1), 0)];
    int so1 = (int)csr1[max(min(t1 + eslot, end1 - 1), 0)];
    float ev0 = (float)el0h[(size_t)so0 * 8 + head];
    float ev1 = (float)el1h[(size_t)so1 * 8 + head];

    // gather: slot-j index broadcast within each 8-lane group via swizzle
    __half2 g0[8], g1[8];
#define LDJ(J)                                                          \
    {                                                                   \
      int sj0 = __builtin_amdgcn_ds_swizzle(so0, ((J) << 5) | 0x18);    \
      int sj1 = __builtin_amdgcn_ds_swizzle(so1, ((J) << 5) | 0x18);    \
      g0[J] = f0[(size_t)sj0 * 64 + lane];                              \
      g1[J] = f1[(size_t)sj1 * 64 + lane];                              \
    }
    LDJ(0) LDJ(1) LDJ(2) LDJ(3) LDJ(4) LDJ(5) LDJ(6) LDJ(7)
#undef LDJ

    float e0 = ev0 + er0h; e0 = fmaxf(e0, 0.2f * e0);
    float p0 = __expf(e0 - bnd0);
    p0 = (t0 + eslot < end0) ? p0 : 0.f;
    float e1 = ev1 + er1h; e1 = fmaxf(e1, 0.2f * e1);
    float p1 = __expf(e1 - bnd1);
    p1 = (t1 + eslot < end1) ? p1 : 0.f;
    ls0 += p0; ls1 += p1;            // own slot only; reduced after loop

    // broadcast p within each 8-lane head group via immediate swizzle
#define ACCJ(J)                                                     \
    {                                                               \
      float pj0 = ds_swz<((J) << 5) | 0x18>(p0);                    \
      float pj1 = ds_swz<((J) << 5) | 0x18>(p1);                    \
      a00 = fmaf(__low2float(g0[J]), pj0, a00);                     \
      a01 = fmaf(__high2float(g0[J]), pj0, a01);                    \
      a10 = fmaf(__low2float(g1[J]), pj1, a10);                     \
      a11 = fmaf(__high2float(g1[J]), pj1, a11);                    \
    }
    ACCJ(0) ACCJ(1) ACCJ(2) ACCJ(3) ACCJ(4) ACCJ(5) ACCJ(6) ACCJ(7)
#undef ACCJ
  }

  // softmax denominator: xor-reduce within each 8-lane head group
  ls0 += ds_swz<(1 << 10) | 0x1F>(ls0);
  ls0 += ds_swz<(2 << 10) | 0x1F>(ls0);
  ls0 += ds_swz<(4 << 10) | 0x1F>(ls0);
  ls1 += ds_swz<(1 << 10) | 0x1F>(ls1);
  ls1 += ds_swz<(2 << 10) | 0x1F>(ls1);
  ls1 += ds_swz<(4 << 10) | 0x1F>(ls1);

  float inv0 = (ls0 > 0.f) ? 1.f / ls0 : 0.f;  // isolated node -> rst = 0
  float inv1 = (ls1 > 0.f) ? 1.f / ls1 : 0.f;
  float t0 = a00 * inv0 + a10 * inv1 + b0[lane * 2] + b1[lane * 2];
  float t1 = a01 * inv0 + a11 * inv1 + b0[lane * 2 + 1] + b1[lane * 2 + 1];
  t0 = (t0 > 0.f) ? t0 : 0.01f * t0;           // leaky_relu 0.01
  t1 = (t1 > 0.f) ? t1 : 0.01f * t1;
  __half2* hh = (__half2*)h1h + (size_t)n * 64 + lane;
  float2 h = __half22float2(*hh);
  h.x += t0; h.y += t1;
  *hh = __floats2half2_rn(h.x, h.y);
}

// ---------------------------------------------------------------------------
extern "C" void kernel_launch(void* const* d_in, const int* in_sizes, int n_in,
                              void* d_out, int out_size, void* d_ws,
                              size_t ws_size, hipStream_t stream) {
  const float* inputs = (const float*)d_in[0];
  const int* src = (const int*)d_in[1];
  const int* dst = (const int*)d_in[2];
  const float* ew1 = (const float*)d_in[3];
  const float* eg = (const float*)d_in[4];
  const float* eb = (const float*)d_in[5];
  const float* ew2 = (const float*)d_in[6];
  const float* gfc = (const float*)d_in[7];
  const float* gal = (const float*)d_in[8];
  const float* gar = (const float*)d_in[9];
  const float* gb = (const float*)d_in[10];
  const float* dw1 = (const float*)d_in[11];
  const float* dg = (const float*)d_in[12];
  const float* db = (const float*)d_in[13];
  const float* dw2 = (const float*)d_in[14];
  float* out = (float*)d_out;

  // ---- workspace layout (~56 MB) ----
  char* p = (char*)d_ws;
  // region A (25.6MB): ybuf_h (MLP phases) | feat0h+feat1h (GAT phase)
  _Float16* feat0h = (_Float16*)p;
  _Float16* feat1h = feat0h + (size_t)NN * 128;
  _Float16* ybuf_h = feat0h;        // alias: MLP and GAT phases don't overlap
  p += (size_t)NN * 128 * 4;
  _Float16* h1h = (_Float16*)p;     p += (size_t)NN * 128 * 2;   // 12.8MB
  _Float16* el0h = (_Float16*)p;    p += (size_t)NN * NHEAD * 2;
  float* er0 = (float*)p;           p += (size_t)NN * NHEAD * 4;
  _Float16* el1h = (_Float16*)p;    p += (size_t)NN * NHEAD * 2;
  float* er1 = (float*)p;           p += (size_t)NN * NHEAD * 4;
  float* stats = (float*)p;         p += 1024 * 4;  // stats_e | stats_d
  float* stats_e = stats;
  float* stats_d = stats + 512;
  _Float16* ew1t = (_Float16*)p;    p += (size_t)64 * 128 * 2;
  _Float16* ew2t = (_Float16*)p;    p += (size_t)128 * 128 * 2;
  _Float16* dw1t = (_Float16*)p;    p += (size_t)128 * 128 * 2;
  _Float16* dw2t = (_Float16*)p;    p += (size_t)32 * 128 * 2;
  _Float16* bt = (_Float16*)p;      p += (size_t)4 * 288 * 128 * 2;
  int* rowptr = (int*)p;            p += (size_t)2 * (NN + 1) * 4;
  unsigned short* csr = (unsigned short*)p;   p += (size_t)2 * EE * 2;
  unsigned* packed = (unsigned*)p;  p += (size_t)2 * EE * 4;    // 6.4MB
  int* bcnt = (int*)p;              p += (size_t)SCT * 4;       // 100KB
  int* totals = (int*)p;            p += 128 * 4;
  unsigned* elmaxAll = (unsigned*)p;  // 64 uints (4 layers x 16)

  const int GB = (NN + 127) / 128;  // 391

  // ---- zero stats BEFORE build (GEMM1 inside build atomically adds) ----
  hipMemsetAsync(stats, 0, 1024 * 4, stream);

  // ---- build (transposes + bhist + embed-GEMM1 merged) + CSR ----
  build_k<<<696, 256, 0, stream>>>(ew1, ew2, dw1, dw2, gfc, gal, gar,
                                   ew1t, ew2t, dw1t, dw2t, bt, elmaxAll,
                                   dst, bcnt, inputs, stats_e, ybuf_h);
  scanA_k<<<SCHUNK, 256, 0, stream>>>(bcnt, totals);
  bscat_k<<<dim3(NBLK, 2), 256, 0, stream>>>(src, dst, bcnt, totals, packed);
  bfin_k<<<2 * NBIN, 256, 0, stream>>>(packed, bcnt, totals, rowptr, csr);

  // ---- embed MLP stage 2: h1h = relu(bn(y))@w2 + relu(bn(y)) ----
  mfma_gemm_k<128, 128, _Float16, true, true, false, true, false>
      <<<GB, 256, 0, stream>>>(ybuf_h, ew2t, stats_e, eg, eb, nullptr,
                               ybuf_h, h1h, nullptr, NN);

  // ---- 4 GAT layers: merged GEMM(+el/er/elmax) then aggregate ----
  for (int l = 0; l < 4; ++l) {
    unsigned* elm = elmaxAll + l * 16;
    feat_gemm_k<<<GB, 256, 0, stream>>>(
        h1h, bt + (size_t)l * 288 * 128, feat0h, feat1h,
        el0h, er0, el1h, er1, elm, NN);
    gat_agg_k<<<(NN + 3) / 4, 256, 0, stream>>>(
        (const __half2*)feat0h, (const __half2*)feat1h, el0h, er0, el1h, er1,
        rowptr, csr, gb + (size_t)(l * 2 + 0) * 128,
        gb + (size_t)(l * 2 + 1) * 128, elm, h1h);
  }

  // ---- decision MLP: y = h1h@dw1 (fp16 store, +stats); out = relu(bn(y))@dw2
  mfma_gemm_k<128, 128, _Float16, false, false, true, true, false>
      <<<GB, 256, 0, stream>>>(h1h, dw1t, nullptr, nullptr, nullptr, stats_d,
                               nullptr, ybuf_h, nullptr, NN);
  mfma_gemm_k<128, 32, _Float16, true, false, false, false, true>
      <<<GB, 256, 0, stream>>>(ybuf_h, dw2t, stats_d, dg, db, nullptr,
                               nullptr, nullptr, out, NN);
}

// Round 10
// 608.032 us; speedup vs baseline: 1.0384x; 1.0193x over previous
//
#include <hip/hip_runtime.h>
#include <hip/hip_fp16.h>
#include <math.h>

#define NN 50000
#define EE 800000
#define NHEAD 8
#define BN_EPS 1e-5f
#define NBIN 196            // ceil(NN/256) coarse buckets (dst>>8)
#define NBLK 128            // edge blocks per relation (R21: 64->128, denser CSR grids)
#define EPB (EE / NBLK)     // 6250 edges per block (exact)
#define SCT (2 * NBIN * NBLK)  // 50176 scan elements = 196*256 exact
#define SCHUNK (SCT / 256)  // 196

typedef _Float16 half8_t __attribute__((ext_vector_type(8)));
typedef float float4_t __attribute__((ext_vector_type(4)));

// monotone float<->uint encoding for atomicMax on signed floats
__device__ __forceinline__ unsigned fenc(float f) {
  unsigned u = __float_as_uint(f);
  return (u & 0x80000000u) ? ~u : (u | 0x80000000u);
}
__device__ __forceinline__ float fdec(unsigned k) {
  return (k & 0x80000000u) ? __uint_as_float(k & 0x7fffffffu)
                           : __uint_as_float(~k);
}

// bn scale/shift from raw sums (stats[c]=sum, stats[128+c]=sumsq)
__device__ __forceinline__ void bn_coef(const float* __restrict__ stats,
                                        const float* __restrict__ gamma,
                                        const float* __restrict__ beta,
                                        int c, float& sc, float& sh) {
  float mean = stats[c] * (1.f / NN);
  float var = fmaxf(stats[128 + c] * (1.f / NN) - mean * mean, 0.f);
  sc = gamma[c] * rsqrtf(var + BN_EPS);
  sh = beta[c] - mean * sc;
}

// static lane swizzle (BitMode): new_lane = ((lane & and) | or) ^ xor, per 32-half
template <int PAT>
__device__ __forceinline__ float ds_swz(float x) {
  return __int_as_float(__builtin_amdgcn_ds_swizzle(__float_as_int(x), PAT));
}

// ---------------------------------------------------------------------------
// MFMA GEMM for embed/decision MLPs — R18 structure (128-row blocks, LDS
// pre-reduced STATS -> one global atomicAdd set per block).
// ---------------------------------------------------------------------------
template <int KDIM, int NC, typename AT, bool ABN, bool RESIDBN, bool STATS,
          bool F16OUT, bool F32OUT>
__global__ __launch_bounds__(256)
void mfma_gemm_k(const AT* __restrict__ A, const _Float16* __restrict__ Bt,
                 const float* __restrict__ bn, const float* __restrict__ gamma,
                 const float* __restrict__ beta, float* __restrict__ statsOut,
                 const _Float16* __restrict__ residh, _Float16* __restrict__ Ch,
                 float* __restrict__ Cf, int M) {
  constexpr int NT = NC / 16;
  const int lane = threadIdx.x & 63, wave = threadIdx.x >> 6;
  const int q = lane >> 4, l16 = lane & 15;
  const int row0 = blockIdx.x * 128 + wave * 32;
  float4_t acc[2][NT];
#pragma unroll
  for (int i = 0; i < 2; ++i)
#pragma unroll
    for (int j = 0; j < NT; ++j) acc[i][j] = (float4_t){0.f, 0.f, 0.f, 0.f};

#pragma unroll
  for (int kk = 0; kk < KDIM / 32; ++kk) {
    float scv[8], shv[8];
    if constexpr (ABN) {
      int kb = kk * 32 + q * 8;
#pragma unroll
      for (int x = 0; x < 8; ++x) bn_coef(bn, gamma, beta, kb + x, scv[x], shv[x]);
    }
    half8_t a[2];
#pragma unroll
    for (int i = 0; i < 2; ++i) {
      int r = row0 + i * 16 + l16;
      r = (r < M) ? r : (M - 1);
      if constexpr (__is_same(AT, _Float16)) {
        half8_t hv = *(const half8_t*)(A + (size_t)r * KDIM + kk * 32 + q * 8);
        if constexpr (ABN) {
#pragma unroll
          for (int x = 0; x < 8; ++x)
            hv[x] = (_Float16)fmaxf((float)hv[x] * scv[x] + shv[x], 0.f);
        }
        a[i] = hv;
      } else {
        const float* ap = (const float*)A + (size_t)r * KDIM + kk * 32 + q * 8;
        float4 v0 = *(const float4*)ap, v1 = *(const float4*)(ap + 4);
        float t[8] = {v0.x, v0.y, v0.z, v0.w, v1.x, v1.y, v1.z, v1.w};
        if constexpr (ABN) {
#pragma unroll
          for (int x = 0; x < 8; ++x) t[x] = fmaxf(t[x] * scv[x] + shv[x], 0.f);
        }
        half8_t hv;
#pragma unroll
        for (int x = 0; x < 8; ++x) hv[x] = (_Float16)t[x];
        a[i] = hv;
      }
    }
#pragma unroll
    for (int j = 0; j < NT; ++j) {
      half8_t b = *(const half8_t*)(Bt + (size_t)(j * 16 + l16) * KDIM + kk * 32 + q * 8);
      acc[0][j] = __builtin_amdgcn_mfma_f32_16x16x32_f16(a[0], b, acc[0][j], 0, 0, 0);
      acc[1][j] = __builtin_amdgcn_mfma_f32_16x16x32_f16(a[1], b, acc[1][j], 0, 0, 0);
    }
  }

  float rsc[NT], rsh[NT];
  if constexpr (RESIDBN) {
#pragma unroll
    for (int j = 0; j < NT; ++j) bn_coef(bn, gamma, beta, j * 16 + l16, rsc[j], rsh[j]);
  }
#pragma unroll
  for (int i = 0; i < 2; ++i)
#pragma unroll
    for (int r = 0; r < 4; ++r) {
      int row = row0 + i * 16 + q * 4 + r;   // C/D: col=lane&15, row=q*4+reg
      if (row >= M) continue;
      float vv[NT];
#pragma unroll
      for (int j = 0; j < NT; ++j) {
        float v = acc[i][j][r];
        if constexpr (RESIDBN) {
          float rv = (float)residh[(size_t)row * NC + j * 16 + l16];
          v += fmaxf(rv * rsc[j] + rsh[j], 0.f);
        }
        vv[j] = v;
        if constexpr (F32OUT) Cf[(size_t)row * NC + j * 16 + l16] = v;
      }
      if constexpr (F16OUT) {
        // pair columns across lane pairs l16^1 (full-line packed __half2 stores)
        const bool ev = (l16 & 1) == 0;
#pragma unroll
        for (int jp = 0; jp < NT / 2; ++jp) {
          float a_ = vv[2 * jp], b_ = vv[2 * jp + 1];
          float an = ds_swz<(1 << 10) | 0x1F>(a_);
          float bn_ = ds_swz<(1 << 10) | 0x1F>(b_);
          float lo = ev ? a_ : bn_;
          float hi = ev ? an : b_;
          int jj = ev ? 2 * jp : 2 * jp + 1;
          __half2 hv = __floats2half2_rn(lo, hi);
          ((__half2*)Ch)[((size_t)row * NC + jj * 16 + (l16 & ~1)) >> 1] = hv;
        }
      }
    }

  if constexpr (STATS) {
    static_assert(!STATS || NT == 8, "stats layout assumes NC=128");
    __shared__ float reds[256];
    reds[threadIdx.x] = 0.f;
    __syncthreads();
    float sc_[NT], sq_[NT];
#pragma unroll
    for (int j = 0; j < NT; ++j) {
      float s = 0.f, qq = 0.f;
#pragma unroll
      for (int i = 0; i < 2; ++i)
#pragma unroll
        for (int r = 0; r < 4; ++r) {
          int row = row0 + i * 16 + q * 4 + r;
          float x = (row < M) ? acc[i][j][r] : 0.f;
          s += x; qq += x * x;
        }
      sc_[j] = s; sq_[j] = qq;
    }
#pragma unroll
    for (int j = 0; j < NT; ++j) {
      sc_[j] += __shfl_xor(sc_[j], 16, 64);
      sq_[j] += __shfl_xor(sq_[j], 16, 64);
      sc_[j] += __shfl_xor(sc_[j], 32, 64);
      sq_[j] += __shfl_xor(sq_[j], 32, 64);
    }
    if (lane < 16) {
#pragma unroll
      for (int j = 0; j < NT; ++j) {
        atomicAdd(&reds[j * 16 + l16], sc_[j]);        // LDS pre-reduction
        atomicAdd(&reds[128 + j * 16 + l16], sq_[j]);
      }
    }
    __syncthreads();
    atomicAdd(&statsOut[threadIdx.x], reds[threadIdx.x]);  // 1 set / block
  }
}

// ---------------------------------------------------------------------------
// Merged per-layer GAT GEMM, NC=288 — R18 structure (unchanged).
// ---------------------------------------------------------------------------
__global__ __launch_bounds__(256)
void feat_gemm_k(const _Float16* __restrict__ A, const _Float16* __restrict__ Bt,
                 _Float16* __restrict__ feat0, _Float16* __restrict__ feat1,
                 _Float16* __restrict__ el0h, float* __restrict__ er0,
                 _Float16* __restrict__ el1h, float* __restrict__ er1,
                 unsigned* __restrict__ elmax, int M) {
  constexpr int NT = 18;
  const int lane = threadIdx.x & 63, wave = threadIdx.x >> 6;
  const int q = lane >> 4, l16 = lane & 15;
  const int row0 = blockIdx.x * 128 + wave * 32;
  __shared__ unsigned redm[16];
  if (threadIdx.x < 16) redm[threadIdx.x] = 0u;
  float4_t acc[2][NT];
#pragma unroll
  for (int i = 0; i < 2; ++i)
#pragma unroll
    for (int j = 0; j < NT; ++j) acc[i][j] = (float4_t){0.f, 0.f, 0.f, 0.f};

#pragma unroll
  for (int kk = 0; kk < 4; ++kk) {
    half8_t a[2];
#pragma unroll
    for (int i = 0; i < 2; ++i) {
      int r = row0 + i * 16 + l16;
      r = (r < M) ? r : (M - 1);
      a[i] = *(const half8_t*)(A + (size_t)r * 128 + kk * 32 + q * 8);
    }
#pragma unroll
    for (int j = 0; j < NT; ++j) {
      half8_t b = *(const half8_t*)(Bt + (size_t)(j * 16 + l16) * 128 + kk * 32 + q * 8);
      acc[0][j] = __builtin_amdgcn_mfma_f32_16x16x32_f16(a[0], b, acc[0][j], 0, 0, 0);
      acc[1][j] = __builtin_amdgcn_mfma_f32_16x16x32_f16(a[1], b, acc[1][j], 0, 0, 0);
    }
  }

#pragma unroll
  for (int i = 0; i < 2; ++i)
#pragma unroll
    for (int r = 0; r < 4; ++r) {
      int row = row0 + i * 16 + q * 4 + r;
      if (row >= M) continue;
      const bool ev = (l16 & 1) == 0;
#pragma unroll
      for (int jp = 0; jp < 8; ++jp) {     // pairs (2jp, 2jp+1); no feat0/1 straddle
        float a_ = acc[i][2 * jp][r], b_ = acc[i][2 * jp + 1][r];
        float an = ds_swz<(1 << 10) | 0x1F>(a_);
        float bn_ = ds_swz<(1 << 10) | 0x1F>(b_);
        float lo = ev ? a_ : bn_;
        float hi = ev ? an : b_;
        int jj = ev ? 2 * jp : 2 * jp + 1;
        __half2 hv = __floats2half2_rn(lo, hi);
        _Float16* fb = (jj < 8) ? feat0 : feat1;
        int colbase = (jj < 8) ? jj * 16 : (jj - 8) * 16;
        ((__half2*)fb)[((size_t)row * 128 + colbase + (l16 & ~1)) >> 1] = hv;
      }
      {
        float v = acc[i][16][r];
        if (l16 < 8) el0h[(size_t)row * 8 + l16] = (_Float16)v;
        else         er0[(size_t)row * 8 + (l16 - 8)] = v;
        v = acc[i][17][r];
        if (l16 < 8) el1h[(size_t)row * 8 + l16] = (_Float16)v;
        else         er1[(size_t)row * 8 + (l16 - 8)] = v;
      }
    }

  float m0 = -1e30f, m1 = -1e30f;
#pragma unroll
  for (int i = 0; i < 2; ++i)
#pragma unroll
    for (int r = 0; r < 4; ++r) {
      m0 = fmaxf(m0, acc[i][16][r]);
      m1 = fmaxf(m1, acc[i][17][r]);
    }
  m0 = fmaxf(m0, __shfl_xor(m0, 16, 64)); m0 = fmaxf(m0, __shfl_xor(m0, 32, 64));
  m1 = fmaxf(m1, __shfl_xor(m1, 16, 64)); m1 = fmaxf(m1, __shfl_xor(m1, 32, 64));
  __syncthreads();                       // redm init visible to all waves
  if (q == 0 && l16 < 8) {
    atomicMax(&redm[l16], fenc(m0));     // LDS pre-reduction across waves
    atomicMax(&redm[8 + l16], fenc(m1));
  }
  __syncthreads();
  if (threadIdx.x < 16) atomicMax(&elmax[threadIdx.x], redm[threadIdx.x]);
}

// ---------------------------------------------------------------------------
// Embed-GEMM1 block body, runs INSIDE build_k (R20 form, unchanged).
// ---------------------------------------------------------------------------
__device__ __forceinline__ void embed1_block(
    const float* __restrict__ A, const float* __restrict__ ew1,
    float* __restrict__ statsOut, _Float16* __restrict__ Ch, int gb, int M) {
  constexpr int NT = 8, BS = 72;  // B row stride in halves
  __shared__ _Float16 blds[128 * BS];
  __shared__ float reds[256];
  for (int L = threadIdx.x; L < 128 * 64; L += 256) {
    int c = L >> 6, k = L & 63;
    blds[c * BS + k] = (_Float16)ew1[k * 128 + c];   // Bt[c][k] = ew1[k][c]
  }
  reds[threadIdx.x] = 0.f;
  __syncthreads();

  const int lane = threadIdx.x & 63, wave = threadIdx.x >> 6;
  const int q = lane >> 4, l16 = lane & 15;
  const int row0 = gb * 128 + wave * 32;
  float4_t acc[2][NT];
#pragma unroll
  for (int i = 0; i < 2; ++i)
#pragma unroll
    for (int j = 0; j < NT; ++j) acc[i][j] = (float4_t){0.f, 0.f, 0.f, 0.f};

#pragma unroll
  for (int kk = 0; kk < 2; ++kk) {
    half8_t a[2];
#pragma unroll
    for (int i = 0; i < 2; ++i) {
      int r = row0 + i * 16 + l16;
      r = (r < M) ? r : (M - 1);
      const float* ap = A + (size_t)r * 64 + kk * 32 + q * 8;
      float4 v0 = *(const float4*)ap, v1 = *(const float4*)(ap + 4);
      float t[8] = {v0.x, v0.y, v0.z, v0.w, v1.x, v1.y, v1.z, v1.w};
      half8_t hv;
#pragma unroll
      for (int x = 0; x < 8; ++x) hv[x] = (_Float16)t[x];
      a[i] = hv;
    }
#pragma unroll
    for (int j = 0; j < NT; ++j) {
      half8_t b = *(const half8_t*)(blds + (size_t)(j * 16 + l16) * BS + kk * 32 + q * 8);
      acc[0][j] = __builtin_amdgcn_mfma_f32_16x16x32_f16(a[0], b, acc[0][j], 0, 0, 0);
      acc[1][j] = __builtin_amdgcn_mfma_f32_16x16x32_f16(a[1], b, acc[1][j], 0, 0, 0);
    }
  }

#pragma unroll
  for (int i = 0; i < 2; ++i)
#pragma unroll
    for (int r = 0; r < 4; ++r) {
      int row = row0 + i * 16 + q * 4 + r;
      if (row >= M) continue;
      float vv[NT];
#pragma unroll
      for (int j = 0; j < NT; ++j) vv[j] = acc[i][j][r];
      const bool ev = (l16 & 1) == 0;
#pragma unroll
      for (int jp = 0; jp < NT / 2; ++jp) {
        float a_ = vv[2 * jp], b_ = vv[2 * jp + 1];
        float an = ds_swz<(1 << 10) | 0x1F>(a_);
        float bn_ = ds_swz<(1 << 10) | 0x1F>(b_);
        float lo = ev ? a_ : bn_;
        float hi = ev ? an : b_;
        int jj = ev ? 2 * jp : 2 * jp + 1;
        __half2 hv = __floats2half2_rn(lo, hi);
        ((__half2*)Ch)[((size_t)row * 128 + jj * 16 + (l16 & ~1)) >> 1] = hv;
      }
    }

  {  // stats: LDS pre-reduction, one global atomicAdd set per block
    float sc_[NT], sq_[NT];
#pragma unroll
    for (int j = 0; j < NT; ++j) {
      float s = 0.f, qq = 0.f;
#pragma unroll
      for (int i = 0; i < 2; ++i)
#pragma unroll
        for (int r = 0; r < 4; ++r) {
          int row = row0 + i * 16 + q * 4 + r;
          float x = (row < M) ? acc[i][j][r] : 0.f;
          s += x; qq += x * x;
        }
      sc_[j] = s; sq_[j] = qq;
    }
#pragma unroll
    for (int j = 0; j < NT; ++j) {
      sc_[j] += __shfl_xor(sc_[j], 16, 64);
      sq_[j] += __shfl_xor(sq_[j], 16, 64);
      sc_[j] += __shfl_xor(sc_[j], 32, 64);
      sq_[j] += __shfl_xor(sq_[j], 32, 64);
    }
    if (lane < 16) {
#pragma unroll
      for (int j = 0; j < NT; ++j) {
        atomicAdd(&reds[j * 16 + l16], sc_[j]);
        atomicAdd(&reds[128 + j * 16 + l16], sq_[j]);
      }
    }
    __syncthreads();
    atomicAdd(&statsOut[threadIdx.x], reds[threadIdx.x]);
  }
}

// ---------------------------------------------------------------------------
// R21 build: tiled transposes + bhist + embed-GEMM1 merged. Grid = 824:
//   0..171   transpose jobs; 172..175 attn rows; 176 zero elmax;
//   177..432 bhist (2*NBLK=256 blocks); 433..823 embed-GEMM1 (391).
// ---------------------------------------------------------------------------
__global__ __launch_bounds__(256)
void build_k(const float* __restrict__ ew1, const float* __restrict__ ew2,
             const float* __restrict__ dw1, const float* __restrict__ dw2,
             const float* __restrict__ gfc, const float* __restrict__ gal,
             const float* __restrict__ gar, _Float16* __restrict__ ew1t,
             _Float16* __restrict__ ew2t, _Float16* __restrict__ dw1t,
             _Float16* __restrict__ dw2t, _Float16* __restrict__ bt,
             unsigned* __restrict__ elmax,
             const int* __restrict__ dstIdx, int* __restrict__ bcnt,
             const float* __restrict__ inputs, float* __restrict__ stats_e,
             _Float16* __restrict__ ybuf_h) {
  const int bid = blockIdx.x;

  if (bid < 172) {  // tiled transpose jobs
    const float* src; _Float16* dst; int K, N, kt, ct;
    if (bid < 8)       { src = ew1; dst = ew1t; K = 64;  N = 128; int t = bid;      kt = t >> 2; ct = t & 3; }
    else if (bid < 24) { src = ew2; dst = ew2t; K = 128; N = 128; int t = bid - 8;  kt = t >> 2; ct = t & 3; }
    else if (bid < 40) { src = dw1; dst = dw1t; K = 128; N = 128; int t = bid - 24; kt = t >> 2; ct = t & 3; }
    else if (bid < 44) { src = dw2; dst = dw2t; K = 128; N = 32;  int t = bid - 40; kt = t;      ct = 0;     }
    else {
      int idx = bid - 44;          // 8 mats x 16 tiles
      int mat = idx >> 4, t = idx & 15;
      int b = mat >> 1, r = mat & 1;
      src = gfc + (size_t)(2 * b + r) * 16384;
      dst = bt + (size_t)b * 288 * 128 + (size_t)r * 128 * 128;
      K = 128; N = 128; kt = t >> 2; ct = t & 3;
    }
    __shared__ float tile[32][33];
    int k0 = kt * 32, c0 = ct * 32;
    int tk = threadIdx.x >> 5, tc = threadIdx.x & 31;  // 8 k-rows x 32 c-cols
#pragma unroll
    for (int it = 0; it < 4; ++it) {
      int k = k0 + tk + it * 8;
      tile[tc][tk + it * 8] = src[(size_t)k * N + c0 + tc];  // coalesced in c
    }
    __syncthreads();
    int ci = threadIdx.x >> 5, ck = threadIdx.x & 31;  // 8 c-rows x 32 k-cols
#pragma unroll
    for (int it = 0; it < 4; ++it) {
      int c = c0 + ci + it * 8;
      dst[(size_t)c * K + k0 + ck] = (_Float16)tile[ci + it * 8][ck];  // coalesced in k
    }
  } else if (bid < 176) {  // attn rows for layer b: bt rows 256..288
    int b = bid - 172;
    _Float16* dstL = bt + (size_t)b * 288 * 128;
    for (int idx = threadIdx.x; idx < 32 * 128; idx += 256) {
      int c = 256 + (idx >> 7), k = idx & 127;
      int sub = c - 256, blk = sub >> 3, h = sub & 7;
      int r = blk >> 1;
      const float* attn = (blk & 1) ? gar : gal;
      const float* W = gfc + (size_t)(2 * b + r) * 16384;
      const float* av = attn + (size_t)(2 * b + r) * 128 + h * 16;
      float s = 0.f;
#pragma unroll
      for (int d = 0; d < 16; ++d) s += W[k * 128 + h * 16 + d] * av[d];
      dstL[c * 128 + k] = (_Float16)s;
    }
  } else if (bid == 176) {  // zero elmax (consumed only by later launches)
    if (threadIdx.x < 64) elmax[threadIdx.x] = 0u;
  } else if (bid < 177 + 2 * NBLK) {  // bhist: 256 blocks
    int j = bid - 177;
    int r = j >> 7, blk = j & (NBLK - 1);
    __shared__ int bins[NBIN];
    for (int i = threadIdx.x; i < NBIN; i += 256) bins[i] = 0;
    __syncthreads();
    const int* d = dstIdx + (size_t)r * EE;
    int e0 = blk * EPB;
    for (int e = e0 + threadIdx.x; e < e0 + EPB; e += 256)
      atomicAdd(&bins[d[e] >> 8], 1);
    __syncthreads();
    for (int i = threadIdx.x; i < NBIN; i += 256)
      bcnt[(size_t)(r * NBIN + i) * NBLK + blk] = bins[i];
  } else {  // embed-GEMM1: 391 blocks
    embed1_block(inputs, ew1, stats_e, ybuf_h, bid - (177 + 2 * NBLK), NN);
  }
}

// ---------------------------------------------------------------------------
// scanA: chunk-local exclusive scan in-place + chunk totals (grid = SCHUNK).
// ---------------------------------------------------------------------------
__global__ __launch_bounds__(256)
void scanA_k(int* __restrict__ bcnt, int* __restrict__ totals) {
  __shared__ int sh[256];
  int b = blockIdx.x, t = threadIdx.x;
  int idx = b * 256 + t;
  int v = bcnt[idx];
  sh[t] = v;
  __syncthreads();
#pragma unroll
  for (int off = 1; off < 256; off <<= 1) {
    int tv = (t >= off) ? sh[t - off] : 0;
    __syncthreads();
    sh[t] += tv;
    __syncthreads();
  }
  bcnt[idx] = sh[t] - v;               // exclusive within chunk
  if (t == 255) totals[b] = sh[t];     // inclusive total
}

// in-block exclusive scan of totals[0..SCHUNK) -> boffs (LDS), all 256 threads
__device__ __forceinline__ void chunk_offsets(const int* __restrict__ totals,
                                              int* __restrict__ boffs) {
  __shared__ int sh[256];
  int t = threadIdx.x;
  int v = (t < SCHUNK) ? totals[t] : 0;
  sh[t] = v;
  __syncthreads();
#pragma unroll
  for (int off = 1; off < 256; off <<= 1) {
    int tv = (t >= off) ? sh[t - off] : 0;
    __syncthreads();
    sh[t] += tv;
    __syncthreads();
  }
  if (t < SCHUNK) boffs[t] = sh[t] - v;  // exclusive
  __syncthreads();
}

__global__ __launch_bounds__(256)
void bscat_k(const int* __restrict__ src, const int* __restrict__ dst,
             const int* __restrict__ bcnt, const int* __restrict__ totals,
             unsigned* __restrict__ packed) {
  int r = blockIdx.y, blk = blockIdx.x;
  __shared__ int base[NBIN];
  __shared__ int boffs[SCHUNK];
  chunk_offsets(totals, boffs);
  for (int i = threadIdx.x; i < NBIN; i += 256) {
    int idx = (r * NBIN + i) * NBLK + blk;
    base[i] = bcnt[idx] + boffs[idx >> 8];
  }
  __syncthreads();
  const int* d = dst + (size_t)r * EE;
  const int* s = src + (size_t)r * EE;
  int e0 = blk * EPB;
  for (int e = e0 + threadIdx.x; e < e0 + EPB; e += 256) {
    int dd = d[e];
    int pos = atomicAdd(&base[dd >> 8], 1);
    packed[pos] = (unsigned)s[e] | ((unsigned)dd << 16);
  }
}

__global__ __launch_bounds__(256)
void bfin_k(const unsigned* __restrict__ packed, const int* __restrict__ bcnt,
            const int* __restrict__ totals, int* __restrict__ rowptr,
            unsigned short* __restrict__ csr) {
  int f = blockIdx.x;  // 0 .. 2*NBIN-1
  int r = f / NBIN, b = f % NBIN;
  __shared__ int boffs[SCHUNK];
  chunk_offsets(totals, boffs);
  __shared__ int deg[256], pref[256], pos[256];
  int start = bcnt[(size_t)f * NBLK] + boffs[(f * NBLK) >> 8];
  int end = (f + 1 < 2 * NBIN)
                ? (bcnt[(size_t)(f + 1) * NBLK] + boffs[((f + 1) * NBLK) >> 8])
                : 2 * EE;
  deg[threadIdx.x] = 0;
  __syncthreads();
  for (int e = start + threadIdx.x; e < end; e += 256)
    atomicAdd(&deg[(packed[e] >> 16) & 255], 1);
  __syncthreads();
  int v = deg[threadIdx.x];
  pref[threadIdx.x] = v;
  __syncthreads();
#pragma unroll
  for (int off = 1; off < 256; off <<= 1) {
    int tv = (threadIdx.x >= off) ? pref[threadIdx.x - off] : 0;
    __syncthreads();
    pref[threadIdx.x] += tv;
    __syncthreads();
  }
  int excl = pref[threadIdx.x] - v;
  int node = b * 256 + threadIdx.x;
  if (node < NN) rowptr[r * (NN + 1) + node] = start - r * EE + excl;
  if (node == NN) rowptr[r * (NN + 1) + NN] = EE;
  pos[threadIdx.x] = start + excl;
  __syncthreads();
  for (int e = start + threadIdx.x; e < end; e += 256) {
    unsigned pk = packed[e];
    int local = (pk >> 16) & 255;
    int p = atomicAdd(&pos[local], 1);
    csr[p] = (unsigned short)(pk & 0xffffu);
  }
}

// ---------------------------------------------------------------------------
// GAT aggregate — R21: each wave handles 2 nodes SEQUENTIALLY (#pragma
// unroll 1 so the compiler cannot interleave them — each node's instruction
// stream stays byte-identical to the proven R18 form). Grid 12500 -> 6250:
// halves block churn, same 4-wave packing granularity.
// ---------------------------------------------------------------------------
__global__ __launch_bounds__(256)
void gat_agg_k(const __half2* __restrict__ f0, const __half2* __restrict__ f1,
               const _Float16* __restrict__ el0h, const float* __restrict__ er0,
               const _Float16* __restrict__ el1h, const float* __restrict__ er1,
               const int* __restrict__ rowptr, const unsigned short* __restrict__ csr,
               const float* __restrict__ b0, const float* __restrict__ b1,
               const unsigned* __restrict__ elmax,
               _Float16* __restrict__ h1h) {
  const int wid = threadIdx.x >> 6;
  const int lane = threadIdx.x & 63;
  const int head = lane >> 3, eslot = lane & 7;
  const int* rp1 = rowptr + (NN + 1);
  const unsigned short* csr1 = csr + EE;

#pragma unroll 1
  for (int s = 0; s < 2; ++s) {
    int n = blockIdx.x * 8 + wid * 2 + s;
    if (n >= NN) continue;
    float er0h = er0[(size_t)n * 8 + head];
    float er1h = er1[(size_t)n * 8 + head];
    float bnd0 = fdec(elmax[head]) + er0h;       bnd0 = fmaxf(bnd0, 0.2f * bnd0);
    float bnd1 = fdec(elmax[8 + head]) + er1h;   bnd1 = fmaxf(bnd1, 0.2f * bnd1);
    int beg0 = rowptr[n], end0 = rowptr[n + 1];
    int beg1 = rp1[n], end1 = rp1[n + 1];
    int len = max(end0 - beg0, end1 - beg1);

    float ls0 = 0.f, a00 = 0.f, a01 = 0.f;
    float ls1 = 0.f, a10 = 0.f, a11 = 0.f;
    for (int t = 0; t < len; t += 8) {
      int t0 = beg0 + t, t1 = beg1 + t;
      int so0 = (int)csr[max(min(t0 + eslot, end0 - 1), 0)];
      int so1 = (int)csr1[max(min(t1 + eslot, end1 - 1), 0)];
      float ev0 = (float)el0h[(size_t)so0 * 8 + head];
      float ev1 = (float)el1h[(size_t)so1 * 8 + head];

      // gather: slot-j index broadcast within each 8-lane group via swizzle
      __half2 g0[8], g1[8];
#define LDJ(J)                                                          \
      {                                                                 \
        int sj0 = __builtin_amdgcn_ds_swizzle(so0, ((J) << 5) | 0x18);  \
        int sj1 = __builtin_amdgcn_ds_swizzle(so1, ((J) << 5) | 0x18);  \
        g0[J] = f0[(size_t)sj0 * 64 + lane];                            \
        g1[J] = f1[(size_t)sj1 * 64 + lane];                            \
      }
      LDJ(0) LDJ(1) LDJ(2) LDJ(3) LDJ(4) LDJ(5) LDJ(6) LDJ(7)
#undef LDJ

      float e0 = ev0 + er0h; e0 = fmaxf(e0, 0.2f * e0);
      float p0 = __expf(e0 - bnd0);
      p0 = (t0 + eslot < end0) ? p0 : 0.f;
      float e1 = ev1 + er1h; e1 = fmaxf(e1, 0.2f * e1);
      float p1 = __expf(e1 - bnd1);
      p1 = (t1 + eslot < end1) ? p1 : 0.f;
      ls0 += p0; ls1 += p1;            // own slot only; reduced after loop

      // broadcast p within each 8-lane head group via immediate swizzle
#define ACCJ(J)                                                     \
      {                                                             \
        float pj0 = ds_swz<((J) << 5) | 0x18>(p0);                  \
        float pj1 = ds_swz<((J) << 5) | 0x18>(p1);                  \
        a00 = fmaf(__low2float(g0[J]), pj0, a00);                   \
        a01 = fmaf(__high2float(g0[J]), pj0, a01);                  \
        a10 = fmaf(__low2float(g1[J]), pj1, a10);                   \
        a11 = fmaf(__high2float(g1[J]), pj1, a11);                  \
      }
      ACCJ(0) ACCJ(1) ACCJ(2) ACCJ(3) ACCJ(4) ACCJ(5) ACCJ(6) ACCJ(7)
#undef ACCJ
    }

    // softmax denominator: xor-reduce within each 8-lane head group
    ls0 += ds_swz<(1 << 10) | 0x1F>(ls0);
    ls0 += ds_swz<(2 << 10) | 0x1F>(ls0);
    ls0 += ds_swz<(4 << 10) | 0x1F>(ls0);
    ls1 += ds_swz<(1 << 10) | 0x1F>(ls1);
    ls1 += ds_swz<(2 << 10) | 0x1F>(ls1);
    ls1 += ds_swz<(4 << 10) | 0x1F>(ls1);

    float inv0 = (ls0 > 0.f) ? 1.f / ls0 : 0.f;  // isolated node -> rst = 0
    float inv1 = (ls1 > 0.f) ? 1.f / ls1 : 0.f;
    float t0 = a00 * inv0 + a10 * inv1 + b0[lane * 2] + b1[lane * 2];
    float t1 = a01 * inv0 + a11 * inv1 + b0[lane * 2 + 1] + b1[lane * 2 + 1];
    t0 = (t0 > 0.f) ? t0 : 0.01f * t0;           // leaky_relu 0.01
    t1 = (t1 > 0.f) ? t1 : 0.01f * t1;
    __half2* hh = (__half2*)h1h + (size_t)n * 64 + lane;
    float2 h = __half22float2(*hh);
    h.x += t0; h.y += t1;
    *hh = __floats2half2_rn(h.x, h.y);
  }
}

// ---------------------------------------------------------------------------
extern "C" void kernel_launch(void* const* d_in, const int* in_sizes, int n_in,
                              void* d_out, int out_size, void* d_ws,
                              size_t ws_size, hipStream_t stream) {
  const float* inputs = (const float*)d_in[0];
  const int* src = (const int*)d_in[1];
  const int* dst = (const int*)d_in[2];
  const float* ew1 = (const float*)d_in[3];
  const float* eg = (const float*)d_in[4];
  const float* eb = (const float*)d_in[5];
  const float* ew2 = (const float*)d_in[6];
  const float* gfc = (const float*)d_in[7];
  const float* gal = (const float*)d_in[8];
  const float* gar = (const float*)d_in[9];
  const float* gb = (const float*)d_in[10];
  const float* dw1 = (const float*)d_in[11];
  const float* dg = (const float*)d_in[12];
  const float* db = (const float*)d_in[13];
  const float* dw2 = (const float*)d_in[14];
  float* out = (float*)d_out;

  // ---- workspace layout (~56 MB) ----
  char* p = (char*)d_ws;
  // region A (25.6MB): ybuf_h (MLP phases) | feat0h+feat1h (GAT phase)
  _Float16* feat0h = (_Float16*)p;
  _Float16* feat1h = feat0h + (size_t)NN * 128;
  _Float16* ybuf_h = feat0h;        // alias: MLP and GAT phases don't overlap
  p += (size_t)NN * 128 * 4;
  _Float16* h1h = (_Float16*)p;     p += (size_t)NN * 128 * 2;   // 12.8MB
  _Float16* el0h = (_Float16*)p;    p += (size_t)NN * NHEAD * 2;
  float* er0 = (float*)p;           p += (size_t)NN * NHEAD * 4;
  _Float16* el1h = (_Float16*)p;    p += (size_t)NN * NHEAD * 2;
  float* er1 = (float*)p;           p += (size_t)NN * NHEAD * 4;
  float* stats = (float*)p;         p += 1024 * 4;  // stats_e | stats_d
  float* stats_e = stats;
  float* stats_d = stats + 512;
  _Float16* ew1t = (_Float16*)p;    p += (size_t)64 * 128 * 2;
  _Float16* ew2t = (_Float16*)p;    p += (size_t)128 * 128 * 2;
  _Float16* dw1t = (_Float16*)p;    p += (size_t)128 * 128 * 2;
  _Float16* dw2t = (_Float16*)p;    p += (size_t)32 * 128 * 2;
  _Float16* bt = (_Float16*)p;      p += (size_t)4 * 288 * 128 * 2;
  int* rowptr = (int*)p;            p += (size_t)2 * (NN + 1) * 4;
  unsigned short* csr = (unsigned short*)p;   p += (size_t)2 * EE * 2;
  unsigned* packed = (unsigned*)p;  p += (size_t)2 * EE * 4;    // 6.4MB
  int* bcnt = (int*)p;              p += (size_t)SCT * 4;       // 200KB
  int* totals = (int*)p;            p += 256 * 4;
  unsigned* elmaxAll = (unsigned*)p;  // 64 uints (4 layers x 16)

  const int GB = (NN + 127) / 128;  // 391

  // ---- zero stats BEFORE build (GEMM1 inside build atomically adds) ----
  hipMemsetAsync(stats, 0, 1024 * 4, stream);

  // ---- build (transposes + bhist + embed-GEMM1 merged) + CSR ----
  build_k<<<177 + 2 * NBLK + GB, 256, 0, stream>>>(
      ew1, ew2, dw1, dw2, gfc, gal, gar,
      ew1t, ew2t, dw1t, dw2t, bt, elmaxAll,
      dst, bcnt, inputs, stats_e, ybuf_h);
  scanA_k<<<SCHUNK, 256, 0, stream>>>(bcnt, totals);
  bscat_k<<<dim3(NBLK, 2), 256, 0, stream>>>(src, dst, bcnt, totals, packed);
  bfin_k<<<2 * NBIN, 256, 0, stream>>>(packed, bcnt, totals, rowptr, csr);

  // ---- embed MLP stage 2: h1h = relu(bn(y))@w2 + relu(bn(y)) ----
  mfma_gemm_k<128, 128, _Float16, true, true, false, true, false>
      <<<GB, 256, 0, stream>>>(ybuf_h, ew2t, stats_e, eg, eb, nullptr,
                               ybuf_h, h1h, nullptr, NN);

  // ---- 4 GAT layers: merged GEMM(+el/er/elmax) then aggregate ----
  for (int l = 0; l < 4; ++l) {
    unsigned* elm = elmaxAll + l * 16;
    feat_gemm_k<<<GB, 256, 0, stream>>>(
        h1h, bt + (size_t)l * 288 * 128, feat0h, feat1h,
        el0h, er0, el1h, er1, elm, NN);
    gat_agg_k<<<(NN + 7) / 8, 256, 0, stream>>>(
        (const __half2*)feat0h, (const __half2*)feat1h, el0h, er0, el1h, er1,
        rowptr, csr, gb + (size_t)(l * 2 + 0) * 128,
        gb + (size_t)(l * 2 + 1) * 128, elm, h1h);
  }

  // ---- decision MLP: y = h1h@dw1 (fp16 store, +stats); out = relu(bn(y))@dw2
  mfma_gemm_k<128, 128, _Float16, false, false, true, true, false>
      <<<GB, 256, 0, stream>>>(h1h, dw1t, nullptr, nullptr, nullptr, stats_d,
                               nullptr, ybuf_h, nullptr, NN);
  mfma_gemm_k<128, 32, _Float16, true, false, false, false, true>
      <<<GB, 256, 0, stream>>>(ybuf_h, dw2t, stats_d, dg, db, nullptr,
                               nullptr, nullptr, out, NN);
}

// Round 11
// 601.747 us; speedup vs baseline: 1.0492x; 1.0104x over previous
//
#include <hip/hip_runtime.h>
#include <hip/hip_fp16.h>
#include <math.h>

#define NN 50000
#define EE 800000
#define NHEAD 8
#define BN_EPS 1e-5f
#define NBIN 196            // ceil(NN/256) coarse buckets (dst>>8)
#define NBLK 128            // edge blocks per relation (R21 form: dense CSR grids)
#define EPB (EE / NBLK)     // 6250 edges per block (exact)
#define SCT (2 * NBIN * NBLK)  // 50176 scan elements = 196*256 exact
#define SCHUNK (SCT / 256)  // 196

typedef _Float16 half8_t __attribute__((ext_vector_type(8)));
typedef float float4_t __attribute__((ext_vector_type(4)));

// monotone float<->uint encoding for atomicMax on signed floats
__device__ __forceinline__ unsigned fenc(float f) {
  unsigned u = __float_as_uint(f);
  return (u & 0x80000000u) ? ~u : (u | 0x80000000u);
}
__device__ __forceinline__ float fdec(unsigned k) {
  return (k & 0x80000000u) ? __uint_as_float(k & 0x7fffffffu)
                           : __uint_as_float(~k);
}

// bn scale/shift from raw sums (stats[c]=sum, stats[128+c]=sumsq)
__device__ __forceinline__ void bn_coef(const float* __restrict__ stats,
                                        const float* __restrict__ gamma,
                                        const float* __restrict__ beta,
                                        int c, float& sc, float& sh) {
  float mean = stats[c] * (1.f / NN);
  float var = fmaxf(stats[128 + c] * (1.f / NN) - mean * mean, 0.f);
  sc = gamma[c] * rsqrtf(var + BN_EPS);
  sh = beta[c] - mean * sc;
}

// static lane swizzle (BitMode): new_lane = ((lane & and) | or) ^ xor, per 32-half
template <int PAT>
__device__ __forceinline__ float ds_swz(float x) {
  return __int_as_float(__builtin_amdgcn_ds_swizzle(__float_as_int(x), PAT));
}

// ---------------------------------------------------------------------------
// MFMA GEMM for embed/decision MLPs — R18 structure (128-row blocks, LDS
// pre-reduced STATS -> one global atomicAdd set per block).
// ---------------------------------------------------------------------------
template <int KDIM, int NC, typename AT, bool ABN, bool RESIDBN, bool STATS,
          bool F16OUT, bool F32OUT>
__global__ __launch_bounds__(256)
void mfma_gemm_k(const AT* __restrict__ A, const _Float16* __restrict__ Bt,
                 const float* __restrict__ bn, const float* __restrict__ gamma,
                 const float* __restrict__ beta, float* __restrict__ statsOut,
                 const _Float16* __restrict__ residh, _Float16* __restrict__ Ch,
                 float* __restrict__ Cf, int M) {
  constexpr int NT = NC / 16;
  const int lane = threadIdx.x & 63, wave = threadIdx.x >> 6;
  const int q = lane >> 4, l16 = lane & 15;
  const int row0 = blockIdx.x * 128 + wave * 32;
  float4_t acc[2][NT];
#pragma unroll
  for (int i = 0; i < 2; ++i)
#pragma unroll
    for (int j = 0; j < NT; ++j) acc[i][j] = (float4_t){0.f, 0.f, 0.f, 0.f};

#pragma unroll
  for (int kk = 0; kk < KDIM / 32; ++kk) {
    float scv[8], shv[8];
    if constexpr (ABN) {
      int kb = kk * 32 + q * 8;
#pragma unroll
      for (int x = 0; x < 8; ++x) bn_coef(bn, gamma, beta, kb + x, scv[x], shv[x]);
    }
    half8_t a[2];
#pragma unroll
    for (int i = 0; i < 2; ++i) {
      int r = row0 + i * 16 + l16;
      r = (r < M) ? r : (M - 1);
      if constexpr (__is_same(AT, _Float16)) {
        half8_t hv = *(const half8_t*)(A + (size_t)r * KDIM + kk * 32 + q * 8);
        if constexpr (ABN) {
#pragma unroll
          for (int x = 0; x < 8; ++x)
            hv[x] = (_Float16)fmaxf((float)hv[x] * scv[x] + shv[x], 0.f);
        }
        a[i] = hv;
      } else {
        const float* ap = (const float*)A + (size_t)r * KDIM + kk * 32 + q * 8;
        float4 v0 = *(const float4*)ap, v1 = *(const float4*)(ap + 4);
        float t[8] = {v0.x, v0.y, v0.z, v0.w, v1.x, v1.y, v1.z, v1.w};
        if constexpr (ABN) {
#pragma unroll
          for (int x = 0; x < 8; ++x) t[x] = fmaxf(t[x] * scv[x] + shv[x], 0.f);
        }
        half8_t hv;
#pragma unroll
        for (int x = 0; x < 8; ++x) hv[x] = (_Float16)t[x];
        a[i] = hv;
      }
    }
#pragma unroll
    for (int j = 0; j < NT; ++j) {
      half8_t b = *(const half8_t*)(Bt + (size_t)(j * 16 + l16) * KDIM + kk * 32 + q * 8);
      acc[0][j] = __builtin_amdgcn_mfma_f32_16x16x32_f16(a[0], b, acc[0][j], 0, 0, 0);
      acc[1][j] = __builtin_amdgcn_mfma_f32_16x16x32_f16(a[1], b, acc[1][j], 0, 0, 0);
    }
  }

  float rsc[NT], rsh[NT];
  if constexpr (RESIDBN) {
#pragma unroll
    for (int j = 0; j < NT; ++j) bn_coef(bn, gamma, beta, j * 16 + l16, rsc[j], rsh[j]);
  }
#pragma unroll
  for (int i = 0; i < 2; ++i)
#pragma unroll
    for (int r = 0; r < 4; ++r) {
      int row = row0 + i * 16 + q * 4 + r;   // C/D: col=lane&15, row=q*4+reg
      if (row >= M) continue;
      float vv[NT];
#pragma unroll
      for (int j = 0; j < NT; ++j) {
        float v = acc[i][j][r];
        if constexpr (RESIDBN) {
          float rv = (float)residh[(size_t)row * NC + j * 16 + l16];
          v += fmaxf(rv * rsc[j] + rsh[j], 0.f);
        }
        vv[j] = v;
        if constexpr (F32OUT) Cf[(size_t)row * NC + j * 16 + l16] = v;
      }
      if constexpr (F16OUT) {
        // pair columns across lane pairs l16^1 (full-line packed __half2 stores)
        const bool ev = (l16 & 1) == 0;
#pragma unroll
        for (int jp = 0; jp < NT / 2; ++jp) {
          float a_ = vv[2 * jp], b_ = vv[2 * jp + 1];
          float an = ds_swz<(1 << 10) | 0x1F>(a_);
          float bn_ = ds_swz<(1 << 10) | 0x1F>(b_);
          float lo = ev ? a_ : bn_;
          float hi = ev ? an : b_;
          int jj = ev ? 2 * jp : 2 * jp + 1;
          __half2 hv = __floats2half2_rn(lo, hi);
          ((__half2*)Ch)[((size_t)row * NC + jj * 16 + (l16 & ~1)) >> 1] = hv;
        }
      }
    }

  if constexpr (STATS) {
    static_assert(!STATS || NT == 8, "stats layout assumes NC=128");
    __shared__ float reds[256];
    reds[threadIdx.x] = 0.f;
    __syncthreads();
    float sc_[NT], sq_[NT];
#pragma unroll
    for (int j = 0; j < NT; ++j) {
      float s = 0.f, qq = 0.f;
#pragma unroll
      for (int i = 0; i < 2; ++i)
#pragma unroll
        for (int r = 0; r < 4; ++r) {
          int row = row0 + i * 16 + q * 4 + r;
          float x = (row < M) ? acc[i][j][r] : 0.f;
          s += x; qq += x * x;
        }
      sc_[j] = s; sq_[j] = qq;
    }
#pragma unroll
    for (int j = 0; j < NT; ++j) {
      sc_[j] += __shfl_xor(sc_[j], 16, 64);
      sq_[j] += __shfl_xor(sq_[j], 16, 64);
      sc_[j] += __shfl_xor(sc_[j], 32, 64);
      sq_[j] += __shfl_xor(sq_[j], 32, 64);
    }
    if (lane < 16) {
#pragma unroll
      for (int j = 0; j < NT; ++j) {
        atomicAdd(&reds[j * 16 + l16], sc_[j]);        // LDS pre-reduction
        atomicAdd(&reds[128 + j * 16 + l16], sq_[j]);
      }
    }
    __syncthreads();
    atomicAdd(&statsOut[threadIdx.x], reds[threadIdx.x]);  // 1 set / block
  }
}

// ---------------------------------------------------------------------------
// Merged per-layer GAT GEMM, NC=288 — R18 structure (unchanged).
// ---------------------------------------------------------------------------
__global__ __launch_bounds__(256)
void feat_gemm_k(const _Float16* __restrict__ A, const _Float16* __restrict__ Bt,
                 _Float16* __restrict__ feat0, _Float16* __restrict__ feat1,
                 _Float16* __restrict__ el0h, float* __restrict__ er0,
                 _Float16* __restrict__ el1h, float* __restrict__ er1,
                 unsigned* __restrict__ elmax, int M) {
  constexpr int NT = 18;
  const int lane = threadIdx.x & 63, wave = threadIdx.x >> 6;
  const int q = lane >> 4, l16 = lane & 15;
  const int row0 = blockIdx.x * 128 + wave * 32;
  __shared__ unsigned redm[16];
  if (threadIdx.x < 16) redm[threadIdx.x] = 0u;
  float4_t acc[2][NT];
#pragma unroll
  for (int i = 0; i < 2; ++i)
#pragma unroll
    for (int j = 0; j < NT; ++j) acc[i][j] = (float4_t){0.f, 0.f, 0.f, 0.f};

#pragma unroll
  for (int kk = 0; kk < 4; ++kk) {
    half8_t a[2];
#pragma unroll
    for (int i = 0; i < 2; ++i) {
      int r = row0 + i * 16 + l16;
      r = (r < M) ? r : (M - 1);
      a[i] = *(const half8_t*)(A + (size_t)r * 128 + kk * 32 + q * 8);
    }
#pragma unroll
    for (int j = 0; j < NT; ++j) {
      half8_t b = *(const half8_t*)(Bt + (size_t)(j * 16 + l16) * 128 + kk * 32 + q * 8);
      acc[0][j] = __builtin_amdgcn_mfma_f32_16x16x32_f16(a[0], b, acc[0][j], 0, 0, 0);
      acc[1][j] = __builtin_amdgcn_mfma_f32_16x16x32_f16(a[1], b, acc[1][j], 0, 0, 0);
    }
  }

#pragma unroll
  for (int i = 0; i < 2; ++i)
#pragma unroll
    for (int r = 0; r < 4; ++r) {
      int row = row0 + i * 16 + q * 4 + r;
      if (row >= M) continue;
      const bool ev = (l16 & 1) == 0;
#pragma unroll
      for (int jp = 0; jp < 8; ++jp) {     // pairs (2jp, 2jp+1); no feat0/1 straddle
        float a_ = acc[i][2 * jp][r], b_ = acc[i][2 * jp + 1][r];
        float an = ds_swz<(1 << 10) | 0x1F>(a_);
        float bn_ = ds_swz<(1 << 10) | 0x1F>(b_);
        float lo = ev ? a_ : bn_;
        float hi = ev ? an : b_;
        int jj = ev ? 2 * jp : 2 * jp + 1;
        __half2 hv = __floats2half2_rn(lo, hi);
        _Float16* fb = (jj < 8) ? feat0 : feat1;
        int colbase = (jj < 8) ? jj * 16 : (jj - 8) * 16;
        ((__half2*)fb)[((size_t)row * 128 + colbase + (l16 & ~1)) >> 1] = hv;
      }
      {
        float v = acc[i][16][r];
        if (l16 < 8) el0h[(size_t)row * 8 + l16] = (_Float16)v;
        else         er0[(size_t)row * 8 + (l16 - 8)] = v;
        v = acc[i][17][r];
        if (l16 < 8) el1h[(size_t)row * 8 + l16] = (_Float16)v;
        else         er1[(size_t)row * 8 + (l16 - 8)] = v;
      }
    }

  float m0 = -1e30f, m1 = -1e30f;
#pragma unroll
  for (int i = 0; i < 2; ++i)
#pragma unroll
    for (int r = 0; r < 4; ++r) {
      m0 = fmaxf(m0, acc[i][16][r]);
      m1 = fmaxf(m1, acc[i][17][r]);
    }
  m0 = fmaxf(m0, __shfl_xor(m0, 16, 64)); m0 = fmaxf(m0, __shfl_xor(m0, 32, 64));
  m1 = fmaxf(m1, __shfl_xor(m1, 16, 64)); m1 = fmaxf(m1, __shfl_xor(m1, 32, 64));
  __syncthreads();                       // redm init visible to all waves
  if (q == 0 && l16 < 8) {
    atomicMax(&redm[l16], fenc(m0));     // LDS pre-reduction across waves
    atomicMax(&redm[8 + l16], fenc(m1));
  }
  __syncthreads();
  if (threadIdx.x < 16) atomicMax(&elmax[threadIdx.x], redm[threadIdx.x]);
}

// ---------------------------------------------------------------------------
// Embed-GEMM1 block body, runs INSIDE build_k (R20 form, unchanged).
// ---------------------------------------------------------------------------
__device__ __forceinline__ void embed1_block(
    const float* __restrict__ A, const float* __restrict__ ew1,
    float* __restrict__ statsOut, _Float16* __restrict__ Ch, int gb, int M) {
  constexpr int NT = 8, BS = 72;  // B row stride in halves
  __shared__ _Float16 blds[128 * BS];
  __shared__ float reds[256];
  for (int L = threadIdx.x; L < 128 * 64; L += 256) {
    int c = L >> 6, k = L & 63;
    blds[c * BS + k] = (_Float16)ew1[k * 128 + c];   // Bt[c][k] = ew1[k][c]
  }
  reds[threadIdx.x] = 0.f;
  __syncthreads();

  const int lane = threadIdx.x & 63, wave = threadIdx.x >> 6;
  const int q = lane >> 4, l16 = lane & 15;
  const int row0 = gb * 128 + wave * 32;
  float4_t acc[2][NT];
#pragma unroll
  for (int i = 0; i < 2; ++i)
#pragma unroll
    for (int j = 0; j < NT; ++j) acc[i][j] = (float4_t){0.f, 0.f, 0.f, 0.f};

#pragma unroll
  for (int kk = 0; kk < 2; ++kk) {
    half8_t a[2];
#pragma unroll
    for (int i = 0; i < 2; ++i) {
      int r = row0 + i * 16 + l16;
      r = (r < M) ? r : (M - 1);
      const float* ap = A + (size_t)r * 64 + kk * 32 + q * 8;
      float4 v0 = *(const float4*)ap, v1 = *(const float4*)(ap + 4);
      float t[8] = {v0.x, v0.y, v0.z, v0.w, v1.x, v1.y, v1.z, v1.w};
      half8_t hv;
#pragma unroll
      for (int x = 0; x < 8; ++x) hv[x] = (_Float16)t[x];
      a[i] = hv;
    }
#pragma unroll
    for (int j = 0; j < NT; ++j) {
      half8_t b = *(const half8_t*)(blds + (size_t)(j * 16 + l16) * BS + kk * 32 + q * 8);
      acc[0][j] = __builtin_amdgcn_mfma_f32_16x16x32_f16(a[0], b, acc[0][j], 0, 0, 0);
      acc[1][j] = __builtin_amdgcn_mfma_f32_16x16x32_f16(a[1], b, acc[1][j], 0, 0, 0);
    }
  }

#pragma unroll
  for (int i = 0; i < 2; ++i)
#pragma unroll
    for (int r = 0; r < 4; ++r) {
      int row = row0 + i * 16 + q * 4 + r;
      if (row >= M) continue;
      float vv[NT];
#pragma unroll
      for (int j = 0; j < NT; ++j) vv[j] = acc[i][j][r];
      const bool ev = (l16 & 1) == 0;
#pragma unroll
      for (int jp = 0; jp < NT / 2; ++jp) {
        float a_ = vv[2 * jp], b_ = vv[2 * jp + 1];
        float an = ds_swz<(1 << 10) | 0x1F>(a_);
        float bn_ = ds_swz<(1 << 10) | 0x1F>(b_);
        float lo = ev ? a_ : bn_;
        float hi = ev ? an : b_;
        int jj = ev ? 2 * jp : 2 * jp + 1;
        __half2 hv = __floats2half2_rn(lo, hi);
        ((__half2*)Ch)[((size_t)row * 128 + jj * 16 + (l16 & ~1)) >> 1] = hv;
      }
    }

  {  // stats: LDS pre-reduction, one global atomicAdd set per block
    float sc_[NT], sq_[NT];
#pragma unroll
    for (int j = 0; j < NT; ++j) {
      float s = 0.f, qq = 0.f;
#pragma unroll
      for (int i = 0; i < 2; ++i)
#pragma unroll
        for (int r = 0; r < 4; ++r) {
          int row = row0 + i * 16 + q * 4 + r;
          float x = (row < M) ? acc[i][j][r] : 0.f;
          s += x; qq += x * x;
        }
      sc_[j] = s; sq_[j] = qq;
    }
#pragma unroll
    for (int j = 0; j < NT; ++j) {
      sc_[j] += __shfl_xor(sc_[j], 16, 64);
      sq_[j] += __shfl_xor(sq_[j], 16, 64);
      sc_[j] += __shfl_xor(sc_[j], 32, 64);
      sq_[j] += __shfl_xor(sq_[j], 32, 64);
    }
    if (lane < 16) {
#pragma unroll
      for (int j = 0; j < NT; ++j) {
        atomicAdd(&reds[j * 16 + l16], sc_[j]);
        atomicAdd(&reds[128 + j * 16 + l16], sq_[j]);
      }
    }
    __syncthreads();
    atomicAdd(&statsOut[threadIdx.x], reds[threadIdx.x]);
  }
}

// ---------------------------------------------------------------------------
// Build (R21 form): tiled transposes + bhist + embed-GEMM1 merged.
//   0..171   transpose jobs; 172..175 attn rows; 176 zero elmax;
//   177..432 bhist (2*NBLK=256 blocks); 433..823 embed-GEMM1 (391).
// ---------------------------------------------------------------------------
__global__ __launch_bounds__(256)
void build_k(const float* __restrict__ ew1, const float* __restrict__ ew2,
             const float* __restrict__ dw1, const float* __restrict__ dw2,
             const float* __restrict__ gfc, const float* __restrict__ gal,
             const float* __restrict__ gar, _Float16* __restrict__ ew1t,
             _Float16* __restrict__ ew2t, _Float16* __restrict__ dw1t,
             _Float16* __restrict__ dw2t, _Float16* __restrict__ bt,
             unsigned* __restrict__ elmax,
             const int* __restrict__ dstIdx, int* __restrict__ bcnt,
             const float* __restrict__ inputs, float* __restrict__ stats_e,
             _Float16* __restrict__ ybuf_h) {
  const int bid = blockIdx.x;

  if (bid < 172) {  // tiled transpose jobs
    const float* src; _Float16* dst; int K, N, kt, ct;
    if (bid < 8)       { src = ew1; dst = ew1t; K = 64;  N = 128; int t = bid;      kt = t >> 2; ct = t & 3; }
    else if (bid < 24) { src = ew2; dst = ew2t; K = 128; N = 128; int t = bid - 8;  kt = t >> 2; ct = t & 3; }
    else if (bid < 40) { src = dw1; dst = dw1t; K = 128; N = 128; int t = bid - 24; kt = t >> 2; ct = t & 3; }
    else if (bid < 44) { src = dw2; dst = dw2t; K = 128; N = 32;  int t = bid - 40; kt = t;      ct = 0;     }
    else {
      int idx = bid - 44;          // 8 mats x 16 tiles
      int mat = idx >> 4, t = idx & 15;
      int b = mat >> 1, r = mat & 1;
      src = gfc + (size_t)(2 * b + r) * 16384;
      dst = bt + (size_t)b * 288 * 128 + (size_t)r * 128 * 128;
      K = 128; N = 128; kt = t >> 2; ct = t & 3;
    }
    __shared__ float tile[32][33];
    int k0 = kt * 32, c0 = ct * 32;
    int tk = threadIdx.x >> 5, tc = threadIdx.x & 31;  // 8 k-rows x 32 c-cols
#pragma unroll
    for (int it = 0; it < 4; ++it) {
      int k = k0 + tk + it * 8;
      tile[tc][tk + it * 8] = src[(size_t)k * N + c0 + tc];  // coalesced in c
    }
    __syncthreads();
    int ci = threadIdx.x >> 5, ck = threadIdx.x & 31;  // 8 c-rows x 32 k-cols
#pragma unroll
    for (int it = 0; it < 4; ++it) {
      int c = c0 + ci + it * 8;
      dst[(size_t)c * K + k0 + ck] = (_Float16)tile[ci + it * 8][ck];  // coalesced in k
    }
  } else if (bid < 176) {  // attn rows for layer b: bt rows 256..288
    int b = bid - 172;
    _Float16* dstL = bt + (size_t)b * 288 * 128;
    for (int idx = threadIdx.x; idx < 32 * 128; idx += 256) {
      int c = 256 + (idx >> 7), k = idx & 127;
      int sub = c - 256, blk = sub >> 3, h = sub & 7;
      int r = blk >> 1;
      const float* attn = (blk & 1) ? gar : gal;
      const float* W = gfc + (size_t)(2 * b + r) * 16384;
      const float* av = attn + (size_t)(2 * b + r) * 128 + h * 16;
      float s = 0.f;
#pragma unroll
      for (int d = 0; d < 16; ++d) s += W[k * 128 + h * 16 + d] * av[d];
      dstL[c * 128 + k] = (_Float16)s;
    }
  } else if (bid == 176) {  // zero elmax (consumed only by later launches)
    if (threadIdx.x < 64) elmax[threadIdx.x] = 0u;
  } else if (bid < 177 + 2 * NBLK) {  // bhist: 256 blocks
    int j = bid - 177;
    int r = j >> 7, blk = j & (NBLK - 1);
    __shared__ int bins[NBIN];
    for (int i = threadIdx.x; i < NBIN; i += 256) bins[i] = 0;
    __syncthreads();
    const int* d = dstIdx + (size_t)r * EE;
    int e0 = blk * EPB;
    for (int e = e0 + threadIdx.x; e < e0 + EPB; e += 256)
      atomicAdd(&bins[d[e] >> 8], 1);
    __syncthreads();
    for (int i = threadIdx.x; i < NBIN; i += 256)
      bcnt[(size_t)(r * NBIN + i) * NBLK + blk] = bins[i];
  } else {  // embed-GEMM1: 391 blocks
    embed1_block(inputs, ew1, stats_e, ybuf_h, bid - (177 + 2 * NBLK), NN);
  }
}

// ---------------------------------------------------------------------------
// scanA: chunk-local exclusive scan in-place + chunk totals (grid = SCHUNK).
// ---------------------------------------------------------------------------
__global__ __launch_bounds__(256)
void scanA_k(int* __restrict__ bcnt, int* __restrict__ totals) {
  __shared__ int sh[256];
  int b = blockIdx.x, t = threadIdx.x;
  int idx = b * 256 + t;
  int v = bcnt[idx];
  sh[t] = v;
  __syncthreads();
#pragma unroll
  for (int off = 1; off < 256; off <<= 1) {
    int tv = (t >= off) ? sh[t - off] : 0;
    __syncthreads();
    sh[t] += tv;
    __syncthreads();
  }
  bcnt[idx] = sh[t] - v;               // exclusive within chunk
  if (t == 255) totals[b] = sh[t];     // inclusive total
}

// in-block exclusive scan of totals[0..SCHUNK) -> boffs (LDS), all 256 threads
__device__ __forceinline__ void chunk_offsets(const int* __restrict__ totals,
                                              int* __restrict__ boffs) {
  __shared__ int sh[256];
  int t = threadIdx.x;
  int v = (t < SCHUNK) ? totals[t] : 0;
  sh[t] = v;
  __syncthreads();
#pragma unroll
  for (int off = 1; off < 256; off <<= 1) {
    int tv = (t >= off) ? sh[t - off] : 0;
    __syncthreads();
    sh[t] += tv;
    __syncthreads();
  }
  if (t < SCHUNK) boffs[t] = sh[t] - v;  // exclusive
  __syncthreads();
}

__global__ __launch_bounds__(256)
void bscat_k(const int* __restrict__ src, const int* __restrict__ dst,
             const int* __restrict__ bcnt, const int* __restrict__ totals,
             unsigned* __restrict__ packed) {
  int r = blockIdx.y, blk = blockIdx.x;
  __shared__ int base[NBIN];
  __shared__ int boffs[SCHUNK];
  chunk_offsets(totals, boffs);
  for (int i = threadIdx.x; i < NBIN; i += 256) {
    int idx = (r * NBIN + i) * NBLK + blk;
    base[i] = bcnt[idx] + boffs[idx >> 8];
  }
  __syncthreads();
  const int* d = dst + (size_t)r * EE;
  const int* s = src + (size_t)r * EE;
  int e0 = blk * EPB;
  for (int e = e0 + threadIdx.x; e < e0 + EPB; e += 256) {
    int dd = d[e];
    int pos = atomicAdd(&base[dd >> 8], 1);
    packed[pos] = (unsigned)s[e] | ((unsigned)dd << 16);
  }
}

__global__ __launch_bounds__(256)
void bfin_k(const unsigned* __restrict__ packed, const int* __restrict__ bcnt,
            const int* __restrict__ totals, int* __restrict__ rowptr,
            unsigned short* __restrict__ csr) {
  int f = blockIdx.x;  // 0 .. 2*NBIN-1
  int r = f / NBIN, b = f % NBIN;
  __shared__ int boffs[SCHUNK];
  chunk_offsets(totals, boffs);
  __shared__ int deg[256], pref[256], pos[256];
  int start = bcnt[(size_t)f * NBLK] + boffs[(f * NBLK) >> 8];
  int end = (f + 1 < 2 * NBIN)
                ? (bcnt[(size_t)(f + 1) * NBLK] + boffs[((f + 1) * NBLK) >> 8])
                : 2 * EE;
  deg[threadIdx.x] = 0;
  __syncthreads();
  for (int e = start + threadIdx.x; e < end; e += 256)
    atomicAdd(&deg[(packed[e] >> 16) & 255], 1);
  __syncthreads();
  int v = deg[threadIdx.x];
  pref[threadIdx.x] = v;
  __syncthreads();
#pragma unroll
  for (int off = 1; off < 256; off <<= 1) {
    int tv = (threadIdx.x >= off) ? pref[threadIdx.x - off] : 0;
    __syncthreads();
    pref[threadIdx.x] += tv;
    __syncthreads();
  }
  int excl = pref[threadIdx.x] - v;
  int node = b * 256 + threadIdx.x;
  if (node < NN) rowptr[r * (NN + 1) + node] = start - r * EE + excl;
  if (node == NN) rowptr[r * (NN + 1) + NN] = EE;
  pos[threadIdx.x] = start + excl;
  __syncthreads();
  for (int e = start + threadIdx.x; e < end; e += 256) {
    unsigned pk = packed[e];
    int local = (pk >> 16) & 255;
    int p = atomicAdd(&pos[local], 1);
    csr[p] = (unsigned short)(pk & 0xffffu);
  }
}

// ---------------------------------------------------------------------------
// GAT aggregate — R22: the R18/R20 kernel VERBATIM (1 node/wave, 4 nodes/
// block, grid 12500). Proven 70.4-70.6 µs / 230.0 MB / 61% occ; every
// structural perturbation (R13/R16/R19/R21) regressed 2-10%. Do not touch.
// ---------------------------------------------------------------------------
__global__ __launch_bounds__(256)
void gat_agg_k(const __half2* __restrict__ f0, const __half2* __restrict__ f1,
               const _Float16* __restrict__ el0h, const float* __restrict__ er0,
               const _Float16* __restrict__ el1h, const float* __restrict__ er1,
               const int* __restrict__ rowptr, const unsigned short* __restrict__ csr,
               const float* __restrict__ b0, const float* __restrict__ b1,
               const unsigned* __restrict__ elmax,
               _Float16* __restrict__ h1h) {
  int n = blockIdx.x * 4 + (threadIdx.x >> 6);
  if (n >= NN) return;
  int lane = threadIdx.x & 63;
  int head = lane >> 3, eslot = lane & 7;
  float er0h = er0[(size_t)n * 8 + head];
  float er1h = er1[(size_t)n * 8 + head];
  float bnd0 = fdec(elmax[head]) + er0h;       bnd0 = fmaxf(bnd0, 0.2f * bnd0);
  float bnd1 = fdec(elmax[8 + head]) + er1h;   bnd1 = fmaxf(bnd1, 0.2f * bnd1);
  int beg0 = rowptr[n], end0 = rowptr[n + 1];
  const int* rp1 = rowptr + (NN + 1);
  int beg1 = rp1[n], end1 = rp1[n + 1];
  const unsigned short* csr1 = csr + EE;
  int len = max(end0 - beg0, end1 - beg1);

  float ls0 = 0.f, a00 = 0.f, a01 = 0.f;
  float ls1 = 0.f, a10 = 0.f, a11 = 0.f;
  for (int t = 0; t < len; t += 8) {
    int t0 = beg0 + t, t1 = beg1 + t;
    int so0 = (int)csr[max(min(t0 + eslot, end0 - 1), 0)];
    int so1 = (int)csr1[max(min(t1 + eslot, end1 - 1), 0)];
    float ev0 = (float)el0h[(size_t)so0 * 8 + head];
    float ev1 = (float)el1h[(size_t)so1 * 8 + head];

    // gather: slot-j index broadcast within each 8-lane group via swizzle
    __half2 g0[8], g1[8];
#define LDJ(J)                                                          \
    {                                                                   \
      int sj0 = __builtin_amdgcn_ds_swizzle(so0, ((J) << 5) | 0x18);    \
      int sj1 = __builtin_amdgcn_ds_swizzle(so1, ((J) << 5) | 0x18);    \
      g0[J] = f0[(size_t)sj0 * 64 + lane];                              \
      g1[J] = f1[(size_t)sj1 * 64 + lane];                              \
    }
    LDJ(0) LDJ(1) LDJ(2) LDJ(3) LDJ(4) LDJ(5) LDJ(6) LDJ(7)
#undef LDJ

    float e0 = ev0 + er0h; e0 = fmaxf(e0, 0.2f * e0);
    float p0 = __expf(e0 - bnd0);
    p0 = (t0 + eslot < end0) ? p0 : 0.f;
    float e1 = ev1 + er1h; e1 = fmaxf(e1, 0.2f * e1);
    float p1 = __expf(e1 - bnd1);
    p1 = (t1 + eslot < end1) ? p1 : 0.f;
    ls0 += p0; ls1 += p1;            // own slot only; reduced after loop

    // broadcast p within each 8-lane head group via immediate swizzle
#define ACCJ(J)                                                     \
    {                                                               \
      float pj0 = ds_swz<((J) << 5) | 0x18>(p0);                    \
      float pj1 = ds_swz<((J) << 5) | 0x18>(p1);                    \
      a00 = fmaf(__low2float(g0[J]), pj0, a00);                     \
      a01 = fmaf(__high2float(g0[J]), pj0, a01);                    \
      a10 = fmaf(__low2float(g1[J]), pj1, a10);                     \
      a11 = fmaf(__high2float(g1[J]), pj1, a11);                    \
    }
    ACCJ(0) ACCJ(1) ACCJ(2) ACCJ(3) ACCJ(4) ACCJ(5) ACCJ(6) ACCJ(7)
#undef ACCJ
  }

  // softmax denominator: xor-reduce within each 8-lane head group
  ls0 += ds_swz<(1 << 10) | 0x1F>(ls0);
  ls0 += ds_swz<(2 << 10) | 0x1F>(ls0);
  ls0 += ds_swz<(4 << 10) | 0x1F>(ls0);
  ls1 += ds_swz<(1 << 10) | 0x1F>(ls1);
  ls1 += ds_swz<(2 << 10) | 0x1F>(ls1);
  ls1 += ds_swz<(4 << 10) | 0x1F>(ls1);

  float inv0 = (ls0 > 0.f) ? 1.f / ls0 : 0.f;  // isolated node -> rst = 0
  float inv1 = (ls1 > 0.f) ? 1.f / ls1 : 0.f;
  float t0 = a00 * inv0 + a10 * inv1 + b0[lane * 2] + b1[lane * 2];
  float t1 = a01 * inv0 + a11 * inv1 + b0[lane * 2 + 1] + b1[lane * 2 + 1];
  t0 = (t0 > 0.f) ? t0 : 0.01f * t0;           // leaky_relu 0.01
  t1 = (t1 > 0.f) ? t1 : 0.01f * t1;
  __half2* hh = (__half2*)h1h + (size_t)n * 64 + lane;
  float2 h = __half22float2(*hh);
  h.x += t0; h.y += t1;
  *hh = __floats2half2_rn(h.x, h.y);
}

// ---------------------------------------------------------------------------
extern "C" void kernel_launch(void* const* d_in, const int* in_sizes, int n_in,
                              void* d_out, int out_size, void* d_ws,
                              size_t ws_size, hipStream_t stream) {
  const float* inputs = (const float*)d_in[0];
  const int* src = (const int*)d_in[1];
  const int* dst = (const int*)d_in[2];
  const float* ew1 = (const float*)d_in[3];
  const float* eg = (const float*)d_in[4];
  const float* eb = (const float*)d_in[5];
  const float* ew2 = (const float*)d_in[6];
  const float* gfc = (const float*)d_in[7];
  const float* gal = (const float*)d_in[8];
  const float* gar = (const float*)d_in[9];
  const float* gb = (const float*)d_in[10];
  const float* dw1 = (const float*)d_in[11];
  const float* dg = (const float*)d_in[12];
  const float* db = (const float*)d_in[13];
  const float* dw2 = (const float*)d_in[14];
  float* out = (float*)d_out;

  // ---- workspace layout (~56 MB) ----
  char* p = (char*)d_ws;
  // region A (25.6MB): ybuf_h (MLP phases) | feat0h+feat1h (GAT phase)
  _Float16* feat0h = (_Float16*)p;
  _Float16* feat1h = feat0h + (size_t)NN * 128;
  _Float16* ybuf_h = feat0h;        // alias: MLP and GAT phases don't overlap
  p += (size_t)NN * 128 * 4;
  _Float16* h1h = (_Float16*)p;     p += (size_t)NN * 128 * 2;   // 12.8MB
  _Float16* el0h = (_Float16*)p;    p += (size_t)NN * NHEAD * 2;
  float* er0 = (float*)p;           p += (size_t)NN * NHEAD * 4;
  _Float16* el1h = (_Float16*)p;    p += (size_t)NN * NHEAD * 2;
  float* er1 = (float*)p;           p += (size_t)NN * NHEAD * 4;
  float* stats = (float*)p;         p += 1024 * 4;  // stats_e | stats_d
  float* stats_e = stats;
  float* stats_d = stats + 512;
  _Float16* ew1t = (_Float16*)p;    p += (size_t)64 * 128 * 2;
  _Float16* ew2t = (_Float16*)p;    p += (size_t)128 * 128 * 2;
  _Float16* dw1t = (_Float16*)p;    p += (size_t)128 * 128 * 2;
  _Float16* dw2t = (_Float16*)p;    p += (size_t)32 * 128 * 2;
  _Float16* bt = (_Float16*)p;      p += (size_t)4 * 288 * 128 * 2;
  int* rowptr = (int*)p;            p += (size_t)2 * (NN + 1) * 4;
  unsigned short* csr = (unsigned short*)p;   p += (size_t)2 * EE * 2;
  unsigned* packed = (unsigned*)p;  p += (size_t)2 * EE * 4;    // 6.4MB
  int* bcnt = (int*)p;              p += (size_t)SCT * 4;       // 200KB
  int* totals = (int*)p;            p += 256 * 4;
  unsigned* elmaxAll = (unsigned*)p;  // 64 uints (4 layers x 16)

  const int GB = (NN + 127) / 128;  // 391

  // ---- zero stats BEFORE build (GEMM1 inside build atomically adds) ----
  hipMemsetAsync(stats, 0, 1024 * 4, stream);

  // ---- build (transposes + bhist + embed-GEMM1 merged) + CSR ----
  build_k<<<177 + 2 * NBLK + GB, 256, 0, stream>>>(
      ew1, ew2, dw1, dw2, gfc, gal, gar,
      ew1t, ew2t, dw1t, dw2t, bt, elmaxAll,
      dst, bcnt, inputs, stats_e, ybuf_h);
  scanA_k<<<SCHUNK, 256, 0, stream>>>(bcnt, totals);
  bscat_k<<<dim3(NBLK, 2), 256, 0, stream>>>(src, dst, bcnt, totals, packed);
  bfin_k<<<2 * NBIN, 256, 0, stream>>>(packed, bcnt, totals, rowptr, csr);

  // ---- embed MLP stage 2: h1h = relu(bn(y))@w2 + relu(bn(y)) ----
  mfma_gemm_k<128, 128, _Float16, true, true, false, true, false>
      <<<GB, 256, 0, stream>>>(ybuf_h, ew2t, stats_e, eg, eb, nullptr,
                               ybuf_h, h1h, nullptr, NN);

  // ---- 4 GAT layers: merged GEMM(+el/er/elmax) then aggregate ----
  for (int l = 0; l < 4; ++l) {
    unsigned* elm = elmaxAll + l * 16;
    feat_gemm_k<<<GB, 256, 0, stream>>>(
        h1h, bt + (size_t)l * 288 * 128, feat0h, feat1h,
        el0h, er0, el1h, er1, elm, NN);
    gat_agg_k<<<(NN + 3) / 4, 256, 0, stream>>>(
        (const __half2*)feat0h, (const __half2*)feat1h, el0h, er0, el1h, er1,
        rowptr, csr, gb + (size_t)(l * 2 + 0) * 128,
        gb + (size_t)(l * 2 + 1) * 128, elm, h1h);
  }

  // ---- decision MLP: y = h1h@dw1 (fp16 store, +stats); out = relu(bn(y))@dw2
  mfma_gemm_k<128, 128, _Float16, false, false, true, true, false>
      <<<GB, 256, 0, stream>>>(h1h, dw1t, nullptr, nullptr, nullptr, stats_d,
                               nullptr, ybuf_h, nullptr, NN);
  mfma_gemm_k<128, 32, _Float16, true, false, false, false, true>
      <<<GB, 256, 0, stream>>>(ybuf_h, dw2t, stats_d, dg, db, nullptr,
                               nullptr, nullptr, out, NN);
}